// Round 2
// baseline (841.704 us; speedup 1.0000x reference)
//
#include <hip/hip_runtime.h>
#include <hip/hip_bf16.h>

#define N_NODES 50000
#define N_EDGES 1600000
#define ET (N_EDGES + N_NODES)   // self-loops appended
#define IN_DIM 256
#define HID 128
#define NCLS 40
#define NEG 0.2f
#define NINF (-1e30f)

// ---------------- CSR build ----------------
__global__ void k_deg(const int* __restrict__ ei, int* __restrict__ deg) {
    int i = blockIdx.x * 256 + threadIdx.x;
    if (i >= ET) return;
    int d = (i < N_EDGES) ? ei[N_EDGES + i] : (i - N_EDGES);
    atomicAdd(&deg[d], 1);
}

__global__ __launch_bounds__(1024) void k_scan(const int* __restrict__ deg,
                                               int* __restrict__ rp,
                                               int* __restrict__ cnt) {
    __shared__ int s[1024];
    int t = threadIdx.x;
    const int CH = (N_NODES + 1023) / 1024;  // 49
    int lo = t * CH;
    int hi = lo + CH; if (hi > N_NODES) hi = N_NODES;
    int local = 0;
    for (int i = lo; i < hi; ++i) local += deg[i];
    s[t] = local;
    __syncthreads();
    for (int off = 1; off < 1024; off <<= 1) {
        int v = (t >= off) ? s[t - off] : 0;
        __syncthreads();
        s[t] += v;
        __syncthreads();
    }
    int run = s[t] - local;  // exclusive prefix of this chunk
    for (int i = lo; i < hi; ++i) { rp[i] = run; cnt[i] = run; run += deg[i]; }
    if (t == 1023) rp[N_NODES] = s[1023];
}

__global__ void k_scatter(const int* __restrict__ ei, int* __restrict__ cnt,
                          int* __restrict__ csr) {
    int i = blockIdx.x * 256 + threadIdx.x;
    if (i >= ET) return;
    int s_, d_;
    if (i < N_EDGES) { s_ = ei[i]; d_ = ei[N_EDGES + i]; }
    else             { s_ = d_ = i - N_EDGES; }
    int pos = atomicAdd(&cnt[d_], 1);
    csr[pos] = s_;
}

// ---------------- Layer 0 GEMM: h0 = x @ W0^T, fused alpha dots ----------------
// block = 128 threads (thread t = output col), 16 nodes per block.
// x accessed with block-uniform indices -> scalar loads; W0 row per-thread from L2.
__global__ __launch_bounds__(128) void k_gemm0(
    const float* __restrict__ x, const float* __restrict__ W0,
    const float* __restrict__ a_s, const float* __restrict__ a_d,
    float* __restrict__ h0, float* __restrict__ as0, float* __restrict__ ad0) {
    __shared__ float red[2][16][2];
    int t = threadIdx.x;
    int n0 = blockIdx.x * 16;
    const float* wr = W0 + (size_t)t * IN_DIM;
    float acc[16];
    #pragma unroll
    for (int n = 0; n < 16; ++n) acc[n] = 0.f;
    for (int k0 = 0; k0 < IN_DIM; k0 += 8) {
        float4 w0v = *(const float4*)(wr + k0);
        float4 w1v = *(const float4*)(wr + k0 + 4);
        #pragma unroll
        for (int n = 0; n < 16; ++n) {
            const float* xr = x + (size_t)(n0 + n) * IN_DIM + k0;  // block-uniform
            float4 x0 = *(const float4*)xr;
            float4 x1 = *(const float4*)(xr + 4);
            acc[n] += x0.x * w0v.x + x0.y * w0v.y + x0.z * w0v.z + x0.w * w0v.w
                    + x1.x * w1v.x + x1.y * w1v.y + x1.z * w1v.z + x1.w * w1v.w;
        }
    }
    float asr = a_s[t];
    float adr = a_d[t];
    int wave = t >> 6, lane = t & 63;
    #pragma unroll
    for (int n = 0; n < 16; ++n) {
        h0[(size_t)(n0 + n) * HID + t] = acc[n];
        float ps = acc[n] * asr, pd = acc[n] * adr;
        #pragma unroll
        for (int off = 32; off; off >>= 1) {
            ps += __shfl_xor(ps, off);
            pd += __shfl_xor(pd, off);
        }
        if (lane == 0) { red[wave][n][0] = ps; red[wave][n][1] = pd; }
    }
    __syncthreads();
    if (t < 16) as0[n0 + t] = red[0][t][0] + red[1][t][0];
    else if (t >= 64 && t < 80) { int n = t - 64; ad0[n0 + n] = red[0][n][1] + red[1][n][1]; }
}

// ---------------- Aggregation layer 0 (C=128): wave per dst node ----------------
// Online-softmax (per-chunk running max) — stable for any input scale.
__global__ __launch_bounds__(256) void k_agg0(
    const float* __restrict__ h0, const float* __restrict__ as, const float* __restrict__ ad,
    const int* __restrict__ rp, const int* __restrict__ csr,
    const float* __restrict__ bias, float* __restrict__ act) {
    int node = blockIdx.x * 4 + (threadIdx.x >> 6);
    int lane = threadIdx.x & 63;
    int start = rp[node], end = rp[node + 1];
    float ad_n = ad[node];
    float accx = 0.f, accy = 0.f, den = 0.f, m = NINF;
    for (int base = start; base < end; base += 64) {
        int mm = end - base; if (mm > 64) mm = 64;
        int s_l = 0; float e_l = NINF;
        if (lane < mm) {
            s_l = csr[base + lane];
            float e = as[s_l] + ad_n;
            e_l = (e > 0.f) ? e : NEG * e;
        }
        float cm = e_l;
        #pragma unroll
        for (int off = 32; off; off >>= 1) cm = fmaxf(cm, __shfl_xor(cm, off));
        float mn = fmaxf(m, cm);
        float f = (m <= NINF) ? 0.f : __expf(m - mn);
        float w_l = (lane < mm) ? __expf(e_l - mn) : 0.f;
        m = mn;
        den = den * f + w_l;
        accx *= f; accy *= f;
        for (int j = 0; j < mm; ++j) {
            float w = __shfl(w_l, j);
            int s = __shfl(s_l, j);
            const float2 hv = *(const float2*)&h0[(size_t)s * HID + lane * 2];
            accx += w * hv.x; accy += w * hv.y;
        }
    }
    #pragma unroll
    for (int off = 32; off; off >>= 1) den += __shfl_xor(den, off);
    float inv = 1.f / fmaxf(den, 1e-16f);
    float r0 = fmaxf(accx * inv + bias[lane * 2], 0.f);      // + bias, relu
    float r1 = fmaxf(accy * inv + bias[lane * 2 + 1], 0.f);
    *(float2*)&act[(size_t)node * HID + lane * 2] = make_float2(r0, r1);
}

// ---------------- Layer 1 GEMM: h1 = act @ W1^T, fused alpha dots ----------------
__global__ __launch_bounds__(128) void k_gemm1(
    const float* __restrict__ act, const float* __restrict__ W1,
    const float* __restrict__ a_s, const float* __restrict__ a_d,
    float* __restrict__ h1, float* __restrict__ as1, float* __restrict__ ad1) {
    __shared__ float w1l[NCLS * HID];
    __shared__ float av[NCLS], adv[NCLS];
    int t = threadIdx.x;
    #pragma unroll
    for (int i = 0; i < 10; ++i) {               // 1280 float4 = 5120 floats
        int j = t + 128 * i;
        ((float4*)w1l)[j] = ((const float4*)W1)[j];
    }
    if (t < NCLS) { av[t] = a_s[t]; adv[t] = a_d[t]; }
    __syncthreads();
    int n = blockIdx.x * 128 + t;
    if (n >= N_NODES) return;
    const float4* ar = (const float4*)(act + (size_t)n * HID);
    float acc[NCLS];
    #pragma unroll
    for (int c = 0; c < NCLS; ++c) acc[c] = 0.f;
    for (int k0 = 0; k0 < HID; k0 += 4) {
        float4 xv = ar[k0 >> 2];
        #pragma unroll
        for (int c = 0; c < NCLS; ++c) {
            const float4 wv = *(const float4*)&w1l[c * HID + k0];
            acc[c] += xv.x * wv.x + xv.y * wv.y + xv.z * wv.z + xv.w * wv.w;
        }
    }
    float ps = 0.f, pd = 0.f;
    #pragma unroll
    for (int c = 0; c < NCLS; ++c) {
        ps += acc[c] * av[c];
        pd += acc[c] * adv[c];
        h1[(size_t)n * NCLS + c] = acc[c];
    }
    as1[n] = ps; ad1[n] = pd;
}

// ---------------- Aggregation layer 1 (C=40) → fp32 output ----------------
__global__ __launch_bounds__(256) void k_agg1(
    const float* __restrict__ h1, const float* __restrict__ as, const float* __restrict__ ad,
    const int* __restrict__ rp, const int* __restrict__ csr,
    const float* __restrict__ bias, float* __restrict__ out) {
    int node = blockIdx.x * 4 + (threadIdx.x >> 6);
    int lane = threadIdx.x & 63;
    int start = rp[node], end = rp[node + 1];
    float ad_n = ad[node];
    float acc = 0.f, den = 0.f, m = NINF;
    for (int base = start; base < end; base += 64) {
        int mm = end - base; if (mm > 64) mm = 64;
        int s_l = 0; float e_l = NINF;
        if (lane < mm) {
            s_l = csr[base + lane];
            float e = as[s_l] + ad_n;
            e_l = (e > 0.f) ? e : NEG * e;
        }
        float cm = e_l;
        #pragma unroll
        for (int off = 32; off; off >>= 1) cm = fmaxf(cm, __shfl_xor(cm, off));
        float mn = fmaxf(m, cm);
        float f = (m <= NINF) ? 0.f : __expf(m - mn);
        float w_l = (lane < mm) ? __expf(e_l - mn) : 0.f;
        m = mn;
        den = den * f + w_l;
        acc *= f;
        for (int j = 0; j < mm; ++j) {
            float w = __shfl(w_l, j);
            int s = __shfl(s_l, j);
            if (lane < NCLS) acc += w * h1[(size_t)s * NCLS + lane];
        }
    }
    #pragma unroll
    for (int off = 32; off; off >>= 1) den += __shfl_xor(den, off);
    if (lane < NCLS) {
        float r = acc / fmaxf(den, 1e-16f) + bias[lane];
        out[(size_t)node * NCLS + lane] = r;
    }
}

extern "C" void kernel_launch(void* const* d_in, const int* in_sizes, int n_in,
                              void* d_out, int out_size, void* d_ws, size_t ws_size,
                              hipStream_t stream) {
    const float* x    = (const float*)d_in[0];
    const int*   ei   = (const int*)d_in[1];
    const float* W0   = (const float*)d_in[2];
    const float* a_s0 = (const float*)d_in[3];
    const float* a_d0 = (const float*)d_in[4];
    const float* b0   = (const float*)d_in[5];
    const float* W1   = (const float*)d_in[6];
    const float* a_s1 = (const float*)d_in[7];
    const float* a_d1 = (const float*)d_in[8];
    const float* b1   = (const float*)d_in[9];

    char* p = (char*)d_ws;
    auto alloc = [&](size_t bytes) { void* q = p; p += (bytes + 255) & ~size_t(255); return q; };
    float* h0   = (float*)alloc((size_t)N_NODES * HID * 4);
    float* act  = (float*)alloc((size_t)N_NODES * HID * 4);
    float* h1   = (float*)alloc((size_t)N_NODES * NCLS * 4);
    float* as0  = (float*)alloc((size_t)N_NODES * 4);
    float* ad0  = (float*)alloc((size_t)N_NODES * 4);
    float* as1  = (float*)alloc((size_t)N_NODES * 4);
    float* ad1  = (float*)alloc((size_t)N_NODES * 4);
    int*   deg  = (int*)alloc((size_t)N_NODES * 4);
    int*   rp   = (int*)alloc((size_t)(N_NODES + 1) * 4);
    int*   cnt  = (int*)alloc((size_t)N_NODES * 4);
    int*   csr  = (int*)alloc((size_t)ET * 4);

    hipMemsetAsync(deg, 0, (size_t)N_NODES * 4, stream);
    k_deg<<<(ET + 255) / 256, 256, 0, stream>>>(ei, deg);
    k_scan<<<1, 1024, 0, stream>>>(deg, rp, cnt);
    k_scatter<<<(ET + 255) / 256, 256, 0, stream>>>(ei, cnt, csr);
    k_gemm0<<<N_NODES / 16, 128, 0, stream>>>(x, W0, a_s0, a_d0, h0, as0, ad0);
    k_agg0<<<N_NODES / 4, 256, 0, stream>>>(h0, as0, ad0, rp, csr, b0, act);
    k_gemm1<<<(N_NODES + 127) / 128, 128, 0, stream>>>(act, W1, a_s1, a_d1, h1, as1, ad1);
    k_agg1<<<N_NODES / 4, 256, 0, stream>>>(h1, as1, ad1, rp, csr, b1, (float*)d_out);
}

// Round 3
// 746.978 us; speedup vs baseline: 1.1268x; 1.1268x over previous
//
#include <hip/hip_runtime.h>
#include <hip/hip_bf16.h>

#define N_NODES 50000
#define N_EDGES 1600000
#define ET (N_EDGES + N_NODES)   // self-loops appended
#define IN_DIM 256
#define HID 128
#define NCLS 40
#define NEG 0.2f
#define NINF (-1e30f)

// ---------------- CSR build ----------------
__global__ void k_deg(const int* __restrict__ ei, int* __restrict__ deg) {
    int i = blockIdx.x * 256 + threadIdx.x;
    if (i >= ET) return;
    int d = (i < N_EDGES) ? ei[N_EDGES + i] : (i - N_EDGES);
    atomicAdd(&deg[d], 1);
}

__global__ __launch_bounds__(1024) void k_scan(const int* __restrict__ deg,
                                               int* __restrict__ rp,
                                               int* __restrict__ cnt) {
    __shared__ int s[1024];
    int t = threadIdx.x;
    const int CH = (N_NODES + 1023) / 1024;  // 49
    int lo = t * CH;
    int hi = lo + CH; if (hi > N_NODES) hi = N_NODES;
    int local = 0;
    for (int i = lo; i < hi; ++i) local += deg[i];
    s[t] = local;
    __syncthreads();
    for (int off = 1; off < 1024; off <<= 1) {
        int v = (t >= off) ? s[t - off] : 0;
        __syncthreads();
        s[t] += v;
        __syncthreads();
    }
    int run = s[t] - local;  // exclusive prefix of this chunk
    for (int i = lo; i < hi; ++i) { rp[i] = run; cnt[i] = run; run += deg[i]; }
    if (t == 1023) rp[N_NODES] = s[1023];
}

__global__ void k_scatter(const int* __restrict__ ei, int* __restrict__ cnt,
                          int* __restrict__ csr) {
    int i = blockIdx.x * 256 + threadIdx.x;
    if (i >= ET) return;
    int s_, d_;
    if (i < N_EDGES) { s_ = ei[i]; d_ = ei[N_EDGES + i]; }
    else             { s_ = d_ = i - N_EDGES; }
    int pos = atomicAdd(&cnt[d_], 1);
    csr[pos] = s_;
}

// ---------------- Layer 0 GEMM: h0 = x @ W0^T, fused alpha dots ----------------
// Register-tiled: 64 nodes x 128 cols per 256-thread block; K chunks of 64.
// K-major LDS tiles (stride 68/132): conflict-free b128 compute reads.
// Thread (tn = t&15, tc = t>>4) owns 4 nodes x 8 cols.
__global__ __launch_bounds__(256) void k_gemm0(
    const float* __restrict__ x, const float* __restrict__ W0,
    const float* __restrict__ a_s, const float* __restrict__ a_d,
    float* __restrict__ h0, float* __restrict__ as0, float* __restrict__ ad0) {
    __shared__ __align__(16) float sx[64 * 68];    // sx[k][n]
    __shared__ __align__(16) float sw[64 * 132];   // sw[k][c]
    int t = threadIdx.x;
    int n0 = blockIdx.x * 64;
    int tn = t & 15, tc = t >> 4;
    float acc[4][8];
    #pragma unroll
    for (int ni = 0; ni < 4; ++ni)
        #pragma unroll
        for (int ci = 0; ci < 8; ++ci) acc[ni][ci] = 0.f;

    for (int k0 = 0; k0 < IN_DIM; k0 += 64) {
        // stage x tile: 64 nodes x 64 k = 1024 float4
        #pragma unroll
        for (int i = 0; i < 4; ++i) {
            int j = i * 256 + t;
            int n = j >> 4, kq = j & 15;
            float4 v = make_float4(0.f, 0.f, 0.f, 0.f);
            if (n0 + n < N_NODES)
                v = *(const float4*)&x[(size_t)(n0 + n) * IN_DIM + k0 + kq * 4];
            int kk = kq * 4;
            sx[(kk + 0) * 68 + n] = v.x;
            sx[(kk + 1) * 68 + n] = v.y;
            sx[(kk + 2) * 68 + n] = v.z;
            sx[(kk + 3) * 68 + n] = v.w;
        }
        // stage W tile: 128 cols x 64 k = 2048 float4
        #pragma unroll
        for (int i = 0; i < 8; ++i) {
            int j = i * 256 + t;
            int c = j >> 4, kq = j & 15;
            float4 v = *(const float4*)&W0[(size_t)c * IN_DIM + k0 + kq * 4];
            int kk = kq * 4;
            sw[(kk + 0) * 132 + c] = v.x;
            sw[(kk + 1) * 132 + c] = v.y;
            sw[(kk + 2) * 132 + c] = v.z;
            sw[(kk + 3) * 132 + c] = v.w;
        }
        __syncthreads();
        #pragma unroll 8
        for (int k = 0; k < 64; ++k) {
            float4 av  = *(const float4*)&sx[k * 68 + tn * 4];
            float4 bv0 = *(const float4*)&sw[k * 132 + tc * 8];
            float4 bv1 = *(const float4*)&sw[k * 132 + tc * 8 + 4];
            float a_[4] = {av.x, av.y, av.z, av.w};
            float b_[8] = {bv0.x, bv0.y, bv0.z, bv0.w, bv1.x, bv1.y, bv1.z, bv1.w};
            #pragma unroll
            for (int ni = 0; ni < 4; ++ni)
                #pragma unroll
                for (int ci = 0; ci < 8; ++ci)
                    acc[ni][ci] += a_[ni] * b_[ci];
        }
        __syncthreads();
    }

    // write h0 (guarded for partial last block)
    #pragma unroll
    for (int ni = 0; ni < 4; ++ni) {
        int n = n0 + tn * 4 + ni;
        if (n < N_NODES) {
            *(float4*)&h0[(size_t)n * HID + tc * 8]     = make_float4(acc[ni][0], acc[ni][1], acc[ni][2], acc[ni][3]);
            *(float4*)&h0[(size_t)n * HID + tc * 8 + 4] = make_float4(acc[ni][4], acc[ni][5], acc[ni][6], acc[ni][7]);
        }
    }
    // fused alpha dots: partial per thread, reduce across the 16 tc groups via LDS
    float avs[8], avd[8];
    #pragma unroll
    for (int ci = 0; ci < 8; ++ci) { avs[ci] = a_s[tc * 8 + ci]; avd[ci] = a_d[tc * 8 + ci]; }
    float* red = sx;  // reuse (post-barrier): red_s[64][16], red_d at +1024
    #pragma unroll
    for (int ni = 0; ni < 4; ++ni) {
        float ps = 0.f, pd = 0.f;
        #pragma unroll
        for (int ci = 0; ci < 8; ++ci) { ps += acc[ni][ci] * avs[ci]; pd += acc[ni][ci] * avd[ci]; }
        red[(tn * 4 + ni) * 16 + tc]        = ps;
        red[1024 + (tn * 4 + ni) * 16 + tc] = pd;
    }
    __syncthreads();
    if (t < 64 && n0 + t < N_NODES) {
        float s = 0.f, d = 0.f;
        #pragma unroll
        for (int q = 0; q < 16; ++q) { s += red[t * 16 + q]; d += red[1024 + t * 16 + q]; }
        as0[n0 + t] = s; ad0[n0 + t] = d;
    }
}

// ---------------- Aggregation layer 0 (C=128): wave per dst node ----------------
__global__ __launch_bounds__(256) void k_agg0(
    const float* __restrict__ h0, const float* __restrict__ as, const float* __restrict__ ad,
    const int* __restrict__ rp, const int* __restrict__ csr,
    const float* __restrict__ bias, float* __restrict__ act) {
    int node = blockIdx.x * 4 + (threadIdx.x >> 6);
    int lane = threadIdx.x & 63;
    int start = rp[node], end = rp[node + 1];
    float ad_n = ad[node];
    float accx = 0.f, accy = 0.f, den = 0.f, m = NINF;
    for (int base = start; base < end; base += 64) {
        int mm = end - base; if (mm > 64) mm = 64;
        int s_l = 0; float e_l = NINF;
        if (lane < mm) {
            s_l = csr[base + lane];
            float e = as[s_l] + ad_n;
            e_l = (e > 0.f) ? e : NEG * e;
        }
        float cm = e_l;
        #pragma unroll
        for (int off = 32; off; off >>= 1) cm = fmaxf(cm, __shfl_xor(cm, off));
        float mn = fmaxf(m, cm);
        float f = (m <= NINF) ? 0.f : __expf(m - mn);
        float w_l = (lane < mm) ? __expf(e_l - mn) : 0.f;
        m = mn;
        den = den * f + w_l;
        accx *= f; accy *= f;
        for (int j = 0; j < mm; ++j) {
            float w = __shfl(w_l, j);
            int s = __shfl(s_l, j);
            const float2 hv = *(const float2*)&h0[(size_t)s * HID + lane * 2];
            accx += w * hv.x; accy += w * hv.y;
        }
    }
    #pragma unroll
    for (int off = 32; off; off >>= 1) den += __shfl_xor(den, off);
    float inv = 1.f / fmaxf(den, 1e-16f);
    float r0 = fmaxf(accx * inv + bias[lane * 2], 0.f);      // + bias, relu
    float r1 = fmaxf(accy * inv + bias[lane * 2 + 1], 0.f);
    *(float2*)&act[(size_t)node * HID + lane * 2] = make_float2(r0, r1);
}

// ---------------- Layer 1 GEMM: h1 = act @ W1^T, fused alpha dots ----------------
__global__ __launch_bounds__(128) void k_gemm1(
    const float* __restrict__ act, const float* __restrict__ W1,
    const float* __restrict__ a_s, const float* __restrict__ a_d,
    float* __restrict__ h1, float* __restrict__ as1, float* __restrict__ ad1) {
    __shared__ float w1l[NCLS * HID];
    __shared__ float av[NCLS], adv[NCLS];
    int t = threadIdx.x;
    #pragma unroll
    for (int i = 0; i < 10; ++i) {               // 1280 float4 = 5120 floats
        int j = t + 128 * i;
        ((float4*)w1l)[j] = ((const float4*)W1)[j];
    }
    if (t < NCLS) { av[t] = a_s[t]; adv[t] = a_d[t]; }
    __syncthreads();
    int n = blockIdx.x * 128 + t;
    if (n >= N_NODES) return;
    const float4* ar = (const float4*)(act + (size_t)n * HID);
    float acc[NCLS];
    #pragma unroll
    for (int c = 0; c < NCLS; ++c) acc[c] = 0.f;
    for (int k0 = 0; k0 < HID; k0 += 4) {
        float4 xv = ar[k0 >> 2];
        #pragma unroll
        for (int c = 0; c < NCLS; ++c) {
            const float4 wv = *(const float4*)&w1l[c * HID + k0];
            acc[c] += xv.x * wv.x + xv.y * wv.y + xv.z * wv.z + xv.w * wv.w;
        }
    }
    float ps = 0.f, pd = 0.f;
    #pragma unroll
    for (int c = 0; c < NCLS; ++c) {
        ps += acc[c] * av[c];
        pd += acc[c] * adv[c];
        h1[(size_t)n * NCLS + c] = acc[c];
    }
    as1[n] = ps; ad1[n] = pd;
}

// ---------------- Aggregation layer 1 (C=40) → fp32 output ----------------
__global__ __launch_bounds__(256) void k_agg1(
    const float* __restrict__ h1, const float* __restrict__ as, const float* __restrict__ ad,
    const int* __restrict__ rp, const int* __restrict__ csr,
    const float* __restrict__ bias, float* __restrict__ out) {
    int node = blockIdx.x * 4 + (threadIdx.x >> 6);
    int lane = threadIdx.x & 63;
    int start = rp[node], end = rp[node + 1];
    float ad_n = ad[node];
    float acc = 0.f, den = 0.f, m = NINF;
    for (int base = start; base < end; base += 64) {
        int mm = end - base; if (mm > 64) mm = 64;
        int s_l = 0; float e_l = NINF;
        if (lane < mm) {
            s_l = csr[base + lane];
            float e = as[s_l] + ad_n;
            e_l = (e > 0.f) ? e : NEG * e;
        }
        float cm = e_l;
        #pragma unroll
        for (int off = 32; off; off >>= 1) cm = fmaxf(cm, __shfl_xor(cm, off));
        float mn = fmaxf(m, cm);
        float f = (m <= NINF) ? 0.f : __expf(m - mn);
        float w_l = (lane < mm) ? __expf(e_l - mn) : 0.f;
        m = mn;
        den = den * f + w_l;
        acc *= f;
        for (int j = 0; j < mm; ++j) {
            float w = __shfl(w_l, j);
            int s = __shfl(s_l, j);
            if (lane < NCLS) acc += w * h1[(size_t)s * NCLS + lane];
        }
    }
    #pragma unroll
    for (int off = 32; off; off >>= 1) den += __shfl_xor(den, off);
    if (lane < NCLS) {
        float r = acc / fmaxf(den, 1e-16f) + bias[lane];
        out[(size_t)node * NCLS + lane] = r;
    }
}

extern "C" void kernel_launch(void* const* d_in, const int* in_sizes, int n_in,
                              void* d_out, int out_size, void* d_ws, size_t ws_size,
                              hipStream_t stream) {
    const float* x    = (const float*)d_in[0];
    const int*   ei   = (const int*)d_in[1];
    const float* W0   = (const float*)d_in[2];
    const float* a_s0 = (const float*)d_in[3];
    const float* a_d0 = (const float*)d_in[4];
    const float* b0   = (const float*)d_in[5];
    const float* W1   = (const float*)d_in[6];
    const float* a_s1 = (const float*)d_in[7];
    const float* a_d1 = (const float*)d_in[8];
    const float* b1   = (const float*)d_in[9];

    char* p = (char*)d_ws;
    auto alloc = [&](size_t bytes) { void* q = p; p += (bytes + 255) & ~size_t(255); return q; };
    float* h0   = (float*)alloc((size_t)N_NODES * HID * 4);
    float* act  = (float*)alloc((size_t)N_NODES * HID * 4);
    float* h1   = (float*)alloc((size_t)N_NODES * NCLS * 4);
    float* as0  = (float*)alloc((size_t)N_NODES * 4);
    float* ad0  = (float*)alloc((size_t)N_NODES * 4);
    float* as1  = (float*)alloc((size_t)N_NODES * 4);
    float* ad1  = (float*)alloc((size_t)N_NODES * 4);
    int*   deg  = (int*)alloc((size_t)N_NODES * 4);
    int*   rp   = (int*)alloc((size_t)(N_NODES + 1) * 4);
    int*   cnt  = (int*)alloc((size_t)N_NODES * 4);
    int*   csr  = (int*)alloc((size_t)ET * 4);

    hipMemsetAsync(deg, 0, (size_t)N_NODES * 4, stream);
    k_deg<<<(ET + 255) / 256, 256, 0, stream>>>(ei, deg);
    k_scan<<<1, 1024, 0, stream>>>(deg, rp, cnt);
    k_scatter<<<(ET + 255) / 256, 256, 0, stream>>>(ei, cnt, csr);
    k_gemm0<<<(N_NODES + 63) / 64, 256, 0, stream>>>(x, W0, a_s0, a_d0, h0, as0, ad0);
    k_agg0<<<N_NODES / 4, 256, 0, stream>>>(h0, as0, ad0, rp, csr, b0, act);
    k_gemm1<<<(N_NODES + 127) / 128, 128, 0, stream>>>(act, W1, a_s1, a_d1, h1, as1, ad1);
    k_agg1<<<N_NODES / 4, 256, 0, stream>>>(h1, as1, ad1, rp, csr, b1, (float*)d_out);
}

// Round 4
// 495.772 us; speedup vs baseline: 1.6978x; 1.5067x over previous
//
#include <hip/hip_runtime.h>
#include <hip/hip_bf16.h>

#define N_NODES 50000
#define N_EDGES 1600000
#define ET (N_EDGES + N_NODES)   // self-loops appended
#define IN_DIM 256
#define HID 128
#define NCLS 40
#define NEG 0.2f
#define NINF (-1e30f)
#define NBUCK 391                // ceil(50000 / 128) buckets of 128 dst nodes
#define CHUNK 4096               // edges per binning workgroup

// ---------------- CSR build: two-level binning (no per-edge global atomics) ----
__global__ __launch_bounds__(256) void k_bin_count(const int* __restrict__ ei,
                                                   int* __restrict__ bcnt) {
    __shared__ int hist[NBUCK];
    int t = threadIdx.x;
    for (int i = t; i < NBUCK; i += 256) hist[i] = 0;
    __syncthreads();
    int base = blockIdx.x * CHUNK;
    #pragma unroll
    for (int j = 0; j < 16; ++j) {
        int i = base + j * 256 + t;
        if (i < ET) {
            int d = (i < N_EDGES) ? ei[N_EDGES + i] : (i - N_EDGES);
            atomicAdd(&hist[d >> 7], 1);
        }
    }
    __syncthreads();
    for (int i = t; i < NBUCK; i += 256) if (hist[i]) atomicAdd(&bcnt[i], hist[i]);
}

__global__ __launch_bounds__(512) void k_bin_scan(const int* __restrict__ bcnt,
                                                  int* __restrict__ cstart,
                                                  int* __restrict__ cursor,
                                                  int* __restrict__ rp) {
    __shared__ int s[512];
    int t = threadIdx.x;
    int v = (t < NBUCK) ? bcnt[t] : 0;
    s[t] = v;
    __syncthreads();
    for (int off = 1; off < 512; off <<= 1) {
        int u = (t >= off) ? s[t - off] : 0;
        __syncthreads();
        s[t] += u;
        __syncthreads();
    }
    int ex = s[t] - v;   // exclusive prefix
    if (t < NBUCK) { cstart[t] = ex; cursor[t] = ex; }
    if (t == 0) { cstart[NBUCK] = ET; rp[N_NODES] = ET; }
}

__global__ __launch_bounds__(256) void k_bin_scatter(const int* __restrict__ ei,
                                                     int* __restrict__ cursor,
                                                     unsigned int* __restrict__ buf) {
    __shared__ int sd[CHUNK];     // staged dst (or -1 past end)
    __shared__ int hist[NBUCK];
    __shared__ int wbase[NBUCK];
    int t = threadIdx.x;
    for (int i = t; i < NBUCK; i += 256) hist[i] = 0;
    __syncthreads();
    int base = blockIdx.x * CHUNK;
    #pragma unroll
    for (int j = 0; j < 16; ++j) {
        int i = base + j * 256 + t;
        int d = -1;
        if (i < ET) d = (i < N_EDGES) ? ei[N_EDGES + i] : (i - N_EDGES);
        sd[j * 256 + t] = d;
        if (d >= 0) atomicAdd(&hist[d >> 7], 1);
    }
    __syncthreads();
    for (int i = t; i < NBUCK; i += 256) {
        int h = hist[i];
        wbase[i] = h ? atomicAdd(&cursor[i], h) : 0;
        hist[i] = 0;              // reuse as running offset
    }
    __syncthreads();
    #pragma unroll
    for (int j = 0; j < 16; ++j) {
        int i = base + j * 256 + t;
        int d = sd[j * 256 + t];
        if (d >= 0) {
            int s_ = (i < N_EDGES) ? ei[i] : d;
            int b = d >> 7;
            int off = atomicAdd(&hist[b], 1);
            buf[wbase[b] + off] = ((unsigned)(d & 127) << 16) | (unsigned)s_;
        }
    }
}

__global__ __launch_bounds__(256) void k_bucket_build(const unsigned int* __restrict__ buf,
                                                      const int* __restrict__ cstart,
                                                      int* __restrict__ rp,
                                                      int* __restrict__ csr) {
    __shared__ int cnt[128], rpl[128], cur[128];
    int b = blockIdx.x;
    int t = threadIdx.x;
    int lo = cstart[b], hi = cstart[b + 1];
    if (t < 128) cnt[t] = 0;
    __syncthreads();
    for (int i = lo + t; i < hi; i += 256) atomicAdd(&cnt[buf[i] >> 16], 1);
    __syncthreads();
    if (t == 0) {
        int run = 0;
        #pragma unroll
        for (int l = 0; l < 128; ++l) { rpl[l] = run; run += cnt[l]; }
    }
    __syncthreads();
    if (t < 128) {
        int node = b * 128 + t;
        if (node < N_NODES) rp[node] = lo + rpl[t];
        cur[t] = 0;
    }
    __syncthreads();
    for (int i = lo + t; i < hi; i += 256) {
        unsigned v = buf[i];
        int dl = v >> 16;
        int off = atomicAdd(&cur[dl], 1);
        csr[lo + rpl[dl] + off] = (int)(v & 0xffffu);
    }
}

// ---------------- Layer 0 GEMM: h0 = x @ W0^T, fused alpha dots ----------------
// Register-tiled: 64 nodes x 128 cols per 256-thread block; K chunks of 64.
__global__ __launch_bounds__(256) void k_gemm0(
    const float* __restrict__ x, const float* __restrict__ W0,
    const float* __restrict__ a_s, const float* __restrict__ a_d,
    float* __restrict__ h0, float* __restrict__ as0, float* __restrict__ ad0) {
    __shared__ __align__(16) float sx[64 * 68];    // sx[k][n]
    __shared__ __align__(16) float sw[64 * 132];   // sw[k][c]
    int t = threadIdx.x;
    int n0 = blockIdx.x * 64;
    int tn = t & 15, tc = t >> 4;
    float acc[4][8];
    #pragma unroll
    for (int ni = 0; ni < 4; ++ni)
        #pragma unroll
        for (int ci = 0; ci < 8; ++ci) acc[ni][ci] = 0.f;

    for (int k0 = 0; k0 < IN_DIM; k0 += 64) {
        #pragma unroll
        for (int i = 0; i < 4; ++i) {
            int j = i * 256 + t;
            int n = j >> 4, kq = j & 15;
            float4 v = make_float4(0.f, 0.f, 0.f, 0.f);
            if (n0 + n < N_NODES)
                v = *(const float4*)&x[(size_t)(n0 + n) * IN_DIM + k0 + kq * 4];
            int kk = kq * 4;
            sx[(kk + 0) * 68 + n] = v.x;
            sx[(kk + 1) * 68 + n] = v.y;
            sx[(kk + 2) * 68 + n] = v.z;
            sx[(kk + 3) * 68 + n] = v.w;
        }
        #pragma unroll
        for (int i = 0; i < 8; ++i) {
            int j = i * 256 + t;
            int c = j >> 4, kq = j & 15;
            float4 v = *(const float4*)&W0[(size_t)c * IN_DIM + k0 + kq * 4];
            int kk = kq * 4;
            sw[(kk + 0) * 132 + c] = v.x;
            sw[(kk + 1) * 132 + c] = v.y;
            sw[(kk + 2) * 132 + c] = v.z;
            sw[(kk + 3) * 132 + c] = v.w;
        }
        __syncthreads();
        #pragma unroll 8
        for (int k = 0; k < 64; ++k) {
            float4 av  = *(const float4*)&sx[k * 68 + tn * 4];
            float4 bv0 = *(const float4*)&sw[k * 132 + tc * 8];
            float4 bv1 = *(const float4*)&sw[k * 132 + tc * 8 + 4];
            float a_[4] = {av.x, av.y, av.z, av.w};
            float b_[8] = {bv0.x, bv0.y, bv0.z, bv0.w, bv1.x, bv1.y, bv1.z, bv1.w};
            #pragma unroll
            for (int ni = 0; ni < 4; ++ni)
                #pragma unroll
                for (int ci = 0; ci < 8; ++ci)
                    acc[ni][ci] += a_[ni] * b_[ci];
        }
        __syncthreads();
    }

    #pragma unroll
    for (int ni = 0; ni < 4; ++ni) {
        int n = n0 + tn * 4 + ni;
        if (n < N_NODES) {
            *(float4*)&h0[(size_t)n * HID + tc * 8]     = make_float4(acc[ni][0], acc[ni][1], acc[ni][2], acc[ni][3]);
            *(float4*)&h0[(size_t)n * HID + tc * 8 + 4] = make_float4(acc[ni][4], acc[ni][5], acc[ni][6], acc[ni][7]);
        }
    }
    float avs[8], avd[8];
    #pragma unroll
    for (int ci = 0; ci < 8; ++ci) { avs[ci] = a_s[tc * 8 + ci]; avd[ci] = a_d[tc * 8 + ci]; }
    float* red = sx;  // reuse (post-barrier)
    #pragma unroll
    for (int ni = 0; ni < 4; ++ni) {
        float ps = 0.f, pd = 0.f;
        #pragma unroll
        for (int ci = 0; ci < 8; ++ci) { ps += acc[ni][ci] * avs[ci]; pd += acc[ni][ci] * avd[ci]; }
        red[(tn * 4 + ni) * 16 + tc]        = ps;
        red[1024 + (tn * 4 + ni) * 16 + tc] = pd;
    }
    __syncthreads();
    if (t < 64 && n0 + t < N_NODES) {
        float s = 0.f, d = 0.f;
        #pragma unroll
        for (int q = 0; q < 16; ++q) { s += red[t * 16 + q]; d += red[1024 + t * 16 + q]; }
        as0[n0 + t] = s; ad0[n0 + t] = d;
    }
}

// ---------------- Aggregation layer 0 (C=128): wave per dst node ----------------
__global__ __launch_bounds__(256) void k_agg0(
    const float* __restrict__ h0, const float* __restrict__ as, const float* __restrict__ ad,
    const int* __restrict__ rp, const int* __restrict__ csr,
    const float* __restrict__ bias, float* __restrict__ act) {
    int node = blockIdx.x * 4 + (threadIdx.x >> 6);
    int lane = threadIdx.x & 63;
    int start = rp[node], end = rp[node + 1];
    float ad_n = ad[node];
    float accx = 0.f, accy = 0.f, den = 0.f, m = NINF;
    for (int base = start; base < end; base += 64) {
        int mm = end - base; if (mm > 64) mm = 64;
        int s_l = 0; float e_l = NINF;
        if (lane < mm) {
            s_l = csr[base + lane];
            float e = as[s_l] + ad_n;
            e_l = (e > 0.f) ? e : NEG * e;
        }
        float cm = e_l;
        #pragma unroll
        for (int off = 32; off; off >>= 1) cm = fmaxf(cm, __shfl_xor(cm, off));
        float mn = fmaxf(m, cm);
        float f = (m <= NINF) ? 0.f : __expf(m - mn);
        float w_l = (lane < mm) ? __expf(e_l - mn) : 0.f;
        m = mn;
        den = den * f + w_l;
        accx *= f; accy *= f;
        for (int j = 0; j < mm; ++j) {
            float w = __shfl(w_l, j);
            int s = __shfl(s_l, j);
            const float2 hv = *(const float2*)&h0[(size_t)s * HID + lane * 2];
            accx += w * hv.x; accy += w * hv.y;
        }
    }
    #pragma unroll
    for (int off = 32; off; off >>= 1) den += __shfl_xor(den, off);
    float inv = 1.f / fmaxf(den, 1e-16f);
    float r0 = fmaxf(accx * inv + bias[lane * 2], 0.f);      // + bias, relu
    float r1 = fmaxf(accy * inv + bias[lane * 2 + 1], 0.f);
    *(float2*)&act[(size_t)node * HID + lane * 2] = make_float2(r0, r1);
}

// ---------------- Layer 1 GEMM: h1 = act @ W1^T, fused alpha dots ----------------
__global__ __launch_bounds__(128) void k_gemm1(
    const float* __restrict__ act, const float* __restrict__ W1,
    const float* __restrict__ a_s, const float* __restrict__ a_d,
    float* __restrict__ h1, float* __restrict__ as1, float* __restrict__ ad1) {
    __shared__ float w1l[NCLS * HID];
    __shared__ float av[NCLS], adv[NCLS];
    int t = threadIdx.x;
    #pragma unroll
    for (int i = 0; i < 10; ++i) {
        int j = t + 128 * i;
        ((float4*)w1l)[j] = ((const float4*)W1)[j];
    }
    if (t < NCLS) { av[t] = a_s[t]; adv[t] = a_d[t]; }
    __syncthreads();
    int n = blockIdx.x * 128 + t;
    if (n >= N_NODES) return;
    const float4* ar = (const float4*)(act + (size_t)n * HID);
    float acc[NCLS];
    #pragma unroll
    for (int c = 0; c < NCLS; ++c) acc[c] = 0.f;
    for (int k0 = 0; k0 < HID; k0 += 4) {
        float4 xv = ar[k0 >> 2];
        #pragma unroll
        for (int c = 0; c < NCLS; ++c) {
            const float4 wv = *(const float4*)&w1l[c * HID + k0];
            acc[c] += xv.x * wv.x + xv.y * wv.y + xv.z * wv.z + xv.w * wv.w;
        }
    }
    float ps = 0.f, pd = 0.f;
    #pragma unroll
    for (int c = 0; c < NCLS; ++c) {
        ps += acc[c] * av[c];
        pd += acc[c] * adv[c];
        h1[(size_t)n * NCLS + c] = acc[c];
    }
    as1[n] = ps; ad1[n] = pd;
}

// ---------------- Aggregation layer 1 (C=40) → fp32 output ----------------
__global__ __launch_bounds__(256) void k_agg1(
    const float* __restrict__ h1, const float* __restrict__ as, const float* __restrict__ ad,
    const int* __restrict__ rp, const int* __restrict__ csr,
    const float* __restrict__ bias, float* __restrict__ out) {
    int node = blockIdx.x * 4 + (threadIdx.x >> 6);
    int lane = threadIdx.x & 63;
    int start = rp[node], end = rp[node + 1];
    float ad_n = ad[node];
    float acc = 0.f, den = 0.f, m = NINF;
    for (int base = start; base < end; base += 64) {
        int mm = end - base; if (mm > 64) mm = 64;
        int s_l = 0; float e_l = NINF;
        if (lane < mm) {
            s_l = csr[base + lane];
            float e = as[s_l] + ad_n;
            e_l = (e > 0.f) ? e : NEG * e;
        }
        float cm = e_l;
        #pragma unroll
        for (int off = 32; off; off >>= 1) cm = fmaxf(cm, __shfl_xor(cm, off));
        float mn = fmaxf(m, cm);
        float f = (m <= NINF) ? 0.f : __expf(m - mn);
        float w_l = (lane < mm) ? __expf(e_l - mn) : 0.f;
        m = mn;
        den = den * f + w_l;
        acc *= f;
        for (int j = 0; j < mm; ++j) {
            float w = __shfl(w_l, j);
            int s = __shfl(s_l, j);
            if (lane < NCLS) acc += w * h1[(size_t)s * NCLS + lane];
        }
    }
    #pragma unroll
    for (int off = 32; off; off >>= 1) den += __shfl_xor(den, off);
    if (lane < NCLS) {
        float r = acc / fmaxf(den, 1e-16f) + bias[lane];
        out[(size_t)node * NCLS + lane] = r;
    }
}

extern "C" void kernel_launch(void* const* d_in, const int* in_sizes, int n_in,
                              void* d_out, int out_size, void* d_ws, size_t ws_size,
                              hipStream_t stream) {
    const float* x    = (const float*)d_in[0];
    const int*   ei   = (const int*)d_in[1];
    const float* W0   = (const float*)d_in[2];
    const float* a_s0 = (const float*)d_in[3];
    const float* a_d0 = (const float*)d_in[4];
    const float* b0   = (const float*)d_in[5];
    const float* W1   = (const float*)d_in[6];
    const float* a_s1 = (const float*)d_in[7];
    const float* a_d1 = (const float*)d_in[8];
    const float* b1   = (const float*)d_in[9];

    char* p = (char*)d_ws;
    auto alloc = [&](size_t bytes) { void* q = p; p += (bytes + 255) & ~size_t(255); return q; };
    float* h0     = (float*)alloc((size_t)N_NODES * HID * 4);
    float* act    = (float*)alloc((size_t)N_NODES * HID * 4);
    float* h1     = (float*)alloc((size_t)N_NODES * NCLS * 4);
    float* as0    = (float*)alloc((size_t)N_NODES * 4);
    float* ad0    = (float*)alloc((size_t)N_NODES * 4);
    float* as1    = (float*)alloc((size_t)N_NODES * 4);
    float* ad1    = (float*)alloc((size_t)N_NODES * 4);
    int*   rp     = (int*)alloc((size_t)(N_NODES + 1) * 4);
    int*   csr    = (int*)alloc((size_t)ET * 4);
    unsigned int* buf = (unsigned int*)alloc((size_t)ET * 4);
    int*   bcnt   = (int*)alloc((size_t)NBUCK * 4);
    int*   cstart = (int*)alloc((size_t)(NBUCK + 1) * 4);
    int*   cursor = (int*)alloc((size_t)NBUCK * 4);

    const int binWGs = (ET + CHUNK - 1) / CHUNK;
    hipMemsetAsync(bcnt, 0, (size_t)NBUCK * 4, stream);
    k_bin_count<<<binWGs, 256, 0, stream>>>(ei, bcnt);
    k_bin_scan<<<1, 512, 0, stream>>>(bcnt, cstart, cursor, rp);
    k_bin_scatter<<<binWGs, 256, 0, stream>>>(ei, cursor, buf);
    k_bucket_build<<<NBUCK, 256, 0, stream>>>(buf, cstart, rp, csr);
    k_gemm0<<<(N_NODES + 63) / 64, 256, 0, stream>>>(x, W0, a_s0, a_d0, h0, as0, ad0);
    k_agg0<<<N_NODES / 4, 256, 0, stream>>>(h0, as0, ad0, rp, csr, b0, act);
    k_gemm1<<<(N_NODES + 127) / 128, 128, 0, stream>>>(act, W1, a_s1, a_d1, h1, as1, ad1);
    k_agg1<<<N_NODES / 4, 256, 0, stream>>>(h1, as1, ad1, rp, csr, b1, (float*)d_out);
}

// Round 5
// 474.997 us; speedup vs baseline: 1.7720x; 1.0437x over previous
//
#include <hip/hip_runtime.h>
#include <hip/hip_bf16.h>

#define N_NODES 50000
#define N_EDGES 1600000
#define ET (N_EDGES + N_NODES)   // self-loops appended
#define IN_DIM 256
#define HID 128
#define NCLS 40
#define NEG 0.2f
#define NINF (-1e30f)
#define NBUCK 391                // ceil(50000 / 128) buckets of 128 dst nodes
#define CHUNK 4096               // edges per binning workgroup

__device__ __forceinline__ unsigned pk2(float a, float b) {
    __hip_bfloat16 ha = __float2bfloat16(a), hb = __float2bfloat16(b);
    unsigned short ua = *(unsigned short*)&ha, ub = *(unsigned short*)&hb;
    return (unsigned)ua | ((unsigned)ub << 16);
}

// ---------------- CSR build: two-level binning (no per-edge global atomics) ----
__global__ __launch_bounds__(256) void k_bin_count(const int* __restrict__ ei,
                                                   int* __restrict__ bcnt) {
    __shared__ int hist[NBUCK];
    int t = threadIdx.x;
    for (int i = t; i < NBUCK; i += 256) hist[i] = 0;
    __syncthreads();
    int base = blockIdx.x * CHUNK;
    #pragma unroll
    for (int j = 0; j < 16; ++j) {
        int i = base + j * 256 + t;
        if (i < ET) {
            int d = (i < N_EDGES) ? ei[N_EDGES + i] : (i - N_EDGES);
            atomicAdd(&hist[d >> 7], 1);
        }
    }
    __syncthreads();
    for (int i = t; i < NBUCK; i += 256) if (hist[i]) atomicAdd(&bcnt[i], hist[i]);
}

__global__ __launch_bounds__(512) void k_bin_scan(const int* __restrict__ bcnt,
                                                  int* __restrict__ cstart,
                                                  int* __restrict__ cursor,
                                                  int* __restrict__ rp) {
    __shared__ int s[512];
    int t = threadIdx.x;
    int v = (t < NBUCK) ? bcnt[t] : 0;
    s[t] = v;
    __syncthreads();
    for (int off = 1; off < 512; off <<= 1) {
        int u = (t >= off) ? s[t - off] : 0;
        __syncthreads();
        s[t] += u;
        __syncthreads();
    }
    int ex = s[t] - v;   // exclusive prefix
    if (t < NBUCK) { cstart[t] = ex; cursor[t] = ex; }
    if (t == 0) { cstart[NBUCK] = ET; rp[N_NODES] = ET; }
}

__global__ __launch_bounds__(256) void k_bin_scatter(const int* __restrict__ ei,
                                                     int* __restrict__ cursor,
                                                     unsigned int* __restrict__ buf) {
    __shared__ int sd[CHUNK];     // staged dst (or -1 past end)
    __shared__ int hist[NBUCK];
    __shared__ int wbase[NBUCK];
    int t = threadIdx.x;
    for (int i = t; i < NBUCK; i += 256) hist[i] = 0;
    __syncthreads();
    int base = blockIdx.x * CHUNK;
    #pragma unroll
    for (int j = 0; j < 16; ++j) {
        int i = base + j * 256 + t;
        int d = -1;
        if (i < ET) d = (i < N_EDGES) ? ei[N_EDGES + i] : (i - N_EDGES);
        sd[j * 256 + t] = d;
        if (d >= 0) atomicAdd(&hist[d >> 7], 1);
    }
    __syncthreads();
    for (int i = t; i < NBUCK; i += 256) {
        int h = hist[i];
        wbase[i] = h ? atomicAdd(&cursor[i], h) : 0;
        hist[i] = 0;              // reuse as running offset
    }
    __syncthreads();
    #pragma unroll
    for (int j = 0; j < 16; ++j) {
        int i = base + j * 256 + t;
        int d = sd[j * 256 + t];
        if (d >= 0) {
            int s_ = (i < N_EDGES) ? ei[i] : d;
            int b = d >> 7;
            int off = atomicAdd(&hist[b], 1);
            buf[wbase[b] + off] = ((unsigned)(d & 127) << 16) | (unsigned)s_;
        }
    }
}

__global__ __launch_bounds__(256) void k_bucket_build(const unsigned int* __restrict__ buf,
                                                      const int* __restrict__ cstart,
                                                      int* __restrict__ rp,
                                                      int* __restrict__ csr) {
    __shared__ int cnt[128], rpl[128], cur[128];
    int b = blockIdx.x;
    int t = threadIdx.x;
    int lo = cstart[b], hi = cstart[b + 1];
    if (t < 128) cnt[t] = 0;
    __syncthreads();
    for (int i = lo + t; i < hi; i += 256) atomicAdd(&cnt[buf[i] >> 16], 1);
    __syncthreads();
    if (t == 0) {
        int run = 0;
        #pragma unroll
        for (int l = 0; l < 128; ++l) { rpl[l] = run; run += cnt[l]; }
    }
    __syncthreads();
    if (t < 128) {
        int node = b * 128 + t;
        if (node < N_NODES) rp[node] = lo + rpl[t];
        cur[t] = 0;
    }
    __syncthreads();
    for (int i = lo + t; i < hi; i += 256) {
        unsigned v = buf[i];
        int dl = v >> 16;
        int off = atomicAdd(&cur[dl], 1);
        csr[lo + rpl[dl] + off] = (int)(v & 0xffffu);
    }
}

// ---------------- Layer 0 GEMM: h0(bf16) = x @ W0^T, fused alpha dots ----------
// Register-tiled: 64 nodes x 128 cols per 256-thread block; K chunks of 64.
__global__ __launch_bounds__(256) void k_gemm0(
    const float* __restrict__ x, const float* __restrict__ W0,
    const float* __restrict__ a_s, const float* __restrict__ a_d,
    unsigned short* __restrict__ h0b, float* __restrict__ as0, float* __restrict__ ad0) {
    __shared__ __align__(16) float sx[64 * 68];    // sx[k][n]
    __shared__ __align__(16) float sw[64 * 132];   // sw[k][c]
    int t = threadIdx.x;
    int n0 = blockIdx.x * 64;
    int tn = t & 15, tc = t >> 4;
    float acc[4][8];
    #pragma unroll
    for (int ni = 0; ni < 4; ++ni)
        #pragma unroll
        for (int ci = 0; ci < 8; ++ci) acc[ni][ci] = 0.f;

    for (int k0 = 0; k0 < IN_DIM; k0 += 64) {
        #pragma unroll
        for (int i = 0; i < 4; ++i) {
            int j = i * 256 + t;
            int n = j >> 4, kq = j & 15;
            float4 v = make_float4(0.f, 0.f, 0.f, 0.f);
            if (n0 + n < N_NODES)
                v = *(const float4*)&x[(size_t)(n0 + n) * IN_DIM + k0 + kq * 4];
            int kk = kq * 4;
            sx[(kk + 0) * 68 + n] = v.x;
            sx[(kk + 1) * 68 + n] = v.y;
            sx[(kk + 2) * 68 + n] = v.z;
            sx[(kk + 3) * 68 + n] = v.w;
        }
        #pragma unroll
        for (int i = 0; i < 8; ++i) {
            int j = i * 256 + t;
            int c = j >> 4, kq = j & 15;
            float4 v = *(const float4*)&W0[(size_t)c * IN_DIM + k0 + kq * 4];
            int kk = kq * 4;
            sw[(kk + 0) * 132 + c] = v.x;
            sw[(kk + 1) * 132 + c] = v.y;
            sw[(kk + 2) * 132 + c] = v.z;
            sw[(kk + 3) * 132 + c] = v.w;
        }
        __syncthreads();
        #pragma unroll 8
        for (int k = 0; k < 64; ++k) {
            float4 av  = *(const float4*)&sx[k * 68 + tn * 4];
            float4 bv0 = *(const float4*)&sw[k * 132 + tc * 8];
            float4 bv1 = *(const float4*)&sw[k * 132 + tc * 8 + 4];
            float a_[4] = {av.x, av.y, av.z, av.w};
            float b_[8] = {bv0.x, bv0.y, bv0.z, bv0.w, bv1.x, bv1.y, bv1.z, bv1.w};
            #pragma unroll
            for (int ni = 0; ni < 4; ++ni)
                #pragma unroll
                for (int ci = 0; ci < 8; ++ci)
                    acc[ni][ci] += a_[ni] * b_[ci];
        }
        __syncthreads();
    }

    // write h0 as packed bf16 (8 cols = one uint4 per node per thread)
    #pragma unroll
    for (int ni = 0; ni < 4; ++ni) {
        int n = n0 + tn * 4 + ni;
        if (n < N_NODES) {
            uint4 pk;
            pk.x = pk2(acc[ni][0], acc[ni][1]);
            pk.y = pk2(acc[ni][2], acc[ni][3]);
            pk.z = pk2(acc[ni][4], acc[ni][5]);
            pk.w = pk2(acc[ni][6], acc[ni][7]);
            *(uint4*)&h0b[(size_t)n * HID + tc * 8] = pk;
        }
    }
    // fused alpha dots from fp32 accumulators (full precision logits)
    float avs[8], avd[8];
    #pragma unroll
    for (int ci = 0; ci < 8; ++ci) { avs[ci] = a_s[tc * 8 + ci]; avd[ci] = a_d[tc * 8 + ci]; }
    float* red = sx;  // reuse (post-barrier)
    #pragma unroll
    for (int ni = 0; ni < 4; ++ni) {
        float ps = 0.f, pd = 0.f;
        #pragma unroll
        for (int ci = 0; ci < 8; ++ci) { ps += acc[ni][ci] * avs[ci]; pd += acc[ni][ci] * avd[ci]; }
        red[(tn * 4 + ni) * 16 + tc]        = ps;
        red[1024 + (tn * 4 + ni) * 16 + tc] = pd;
    }
    __syncthreads();
    if (t < 64 && n0 + t < N_NODES) {
        float s = 0.f, d = 0.f;
        #pragma unroll
        for (int q = 0; q < 16; ++q) { s += red[t * 16 + q]; d += red[1024 + t * 16 + q]; }
        as0[n0 + t] = s; ad0[n0 + t] = d;
    }
}

// ---------------- Aggregation layer 0 (C=128, bf16 h0): wave per dst node ------
__global__ __launch_bounds__(256) void k_agg0(
    const unsigned int* __restrict__ h0u, const float* __restrict__ as, const float* __restrict__ ad,
    const int* __restrict__ rp, const int* __restrict__ csr,
    const float* __restrict__ bias, float* __restrict__ act) {
    int node = blockIdx.x * 4 + (threadIdx.x >> 6);
    int lane = threadIdx.x & 63;
    int start = rp[node], end = rp[node + 1];
    float ad_n = ad[node];
    float accx = 0.f, accy = 0.f, den = 0.f, m = NINF;
    for (int base = start; base < end; base += 64) {
        int mm = end - base; if (mm > 64) mm = 64;
        int s_l = 0; float e_l = NINF;
        if (lane < mm) {
            s_l = csr[base + lane];
            float e = as[s_l] + ad_n;
            e_l = (e > 0.f) ? e : NEG * e;
        }
        float cm = e_l;
        #pragma unroll
        for (int off = 32; off; off >>= 1) cm = fmaxf(cm, __shfl_xor(cm, off));
        float mn = fmaxf(m, cm);
        float f = (m <= NINF) ? 0.f : __expf(m - mn);
        float w_l = (lane < mm) ? __expf(e_l - mn) : 0.f;
        m = mn;
        den = den * f + w_l;
        accx *= f; accy *= f;
        for (int j = 0; j < mm; ++j) {
            float w = __shfl(w_l, j);
            int s = __shfl(s_l, j);
            unsigned u = h0u[(size_t)s * 64 + lane];     // 2 bf16: cols 2*lane, 2*lane+1
            accx += w * __uint_as_float(u << 16);
            accy += w * __uint_as_float(u & 0xffff0000u);
        }
    }
    #pragma unroll
    for (int off = 32; off; off >>= 1) den += __shfl_xor(den, off);
    float inv = 1.f / fmaxf(den, 1e-16f);
    float r0 = fmaxf(accx * inv + bias[lane * 2], 0.f);      // + bias, relu
    float r1 = fmaxf(accy * inv + bias[lane * 2 + 1], 0.f);
    *(float2*)&act[(size_t)node * HID + lane * 2] = make_float2(r0, r1);
}

// ---------------- Layer 1 GEMM: h1 = act @ W1^T, fused alpha dots ----------------
__global__ __launch_bounds__(128) void k_gemm1(
    const float* __restrict__ act, const float* __restrict__ W1,
    const float* __restrict__ a_s, const float* __restrict__ a_d,
    float* __restrict__ h1, float* __restrict__ as1, float* __restrict__ ad1) {
    __shared__ float w1l[NCLS * HID];
    __shared__ float av[NCLS], adv[NCLS];
    int t = threadIdx.x;
    #pragma unroll
    for (int i = 0; i < 10; ++i) {
        int j = t + 128 * i;
        ((float4*)w1l)[j] = ((const float4*)W1)[j];
    }
    if (t < NCLS) { av[t] = a_s[t]; adv[t] = a_d[t]; }
    __syncthreads();
    int n = blockIdx.x * 128 + t;
    if (n >= N_NODES) return;
    const float4* ar = (const float4*)(act + (size_t)n * HID);
    float acc[NCLS];
    #pragma unroll
    for (int c = 0; c < NCLS; ++c) acc[c] = 0.f;
    for (int k0 = 0; k0 < HID; k0 += 4) {
        float4 xv = ar[k0 >> 2];
        #pragma unroll
        for (int c = 0; c < NCLS; ++c) {
            const float4 wv = *(const float4*)&w1l[c * HID + k0];
            acc[c] += xv.x * wv.x + xv.y * wv.y + xv.z * wv.z + xv.w * wv.w;
        }
    }
    float ps = 0.f, pd = 0.f;
    #pragma unroll
    for (int c = 0; c < NCLS; ++c) {
        ps += acc[c] * av[c];
        pd += acc[c] * adv[c];
        h1[(size_t)n * NCLS + c] = acc[c];
    }
    as1[n] = ps; ad1[n] = pd;
}

// ---------------- Aggregation layer 1 (C=40) → fp32 output ----------------
__global__ __launch_bounds__(256) void k_agg1(
    const float* __restrict__ h1, const float* __restrict__ as, const float* __restrict__ ad,
    const int* __restrict__ rp, const int* __restrict__ csr,
    const float* __restrict__ bias, float* __restrict__ out) {
    int node = blockIdx.x * 4 + (threadIdx.x >> 6);
    int lane = threadIdx.x & 63;
    int start = rp[node], end = rp[node + 1];
    float ad_n = ad[node];
    float acc = 0.f, den = 0.f, m = NINF;
    for (int base = start; base < end; base += 64) {
        int mm = end - base; if (mm > 64) mm = 64;
        int s_l = 0; float e_l = NINF;
        if (lane < mm) {
            s_l = csr[base + lane];
            float e = as[s_l] + ad_n;
            e_l = (e > 0.f) ? e : NEG * e;
        }
        float cm = e_l;
        #pragma unroll
        for (int off = 32; off; off >>= 1) cm = fmaxf(cm, __shfl_xor(cm, off));
        float mn = fmaxf(m, cm);
        float f = (m <= NINF) ? 0.f : __expf(m - mn);
        float w_l = (lane < mm) ? __expf(e_l - mn) : 0.f;
        m = mn;
        den = den * f + w_l;
        acc *= f;
        for (int j = 0; j < mm; ++j) {
            float w = __shfl(w_l, j);
            int s = __shfl(s_l, j);
            if (lane < NCLS) acc += w * h1[(size_t)s * NCLS + lane];
        }
    }
    #pragma unroll
    for (int off = 32; off; off >>= 1) den += __shfl_xor(den, off);
    if (lane < NCLS) {
        float r = acc / fmaxf(den, 1e-16f) + bias[lane];
        out[(size_t)node * NCLS + lane] = r;
    }
}

extern "C" void kernel_launch(void* const* d_in, const int* in_sizes, int n_in,
                              void* d_out, int out_size, void* d_ws, size_t ws_size,
                              hipStream_t stream) {
    const float* x    = (const float*)d_in[0];
    const int*   ei   = (const int*)d_in[1];
    const float* W0   = (const float*)d_in[2];
    const float* a_s0 = (const float*)d_in[3];
    const float* a_d0 = (const float*)d_in[4];
    const float* b0   = (const float*)d_in[5];
    const float* W1   = (const float*)d_in[6];
    const float* a_s1 = (const float*)d_in[7];
    const float* a_d1 = (const float*)d_in[8];
    const float* b1   = (const float*)d_in[9];

    char* p = (char*)d_ws;
    auto alloc = [&](size_t bytes) { void* q = p; p += (bytes + 255) & ~size_t(255); return q; };
    unsigned short* h0b = (unsigned short*)alloc((size_t)N_NODES * HID * 2);  // bf16
    float* act    = (float*)alloc((size_t)N_NODES * HID * 4);
    float* h1     = (float*)alloc((size_t)N_NODES * NCLS * 4);
    float* as0    = (float*)alloc((size_t)N_NODES * 4);
    float* ad0    = (float*)alloc((size_t)N_NODES * 4);
    float* as1    = (float*)alloc((size_t)N_NODES * 4);
    float* ad1    = (float*)alloc((size_t)N_NODES * 4);
    int*   rp     = (int*)alloc((size_t)(N_NODES + 1) * 4);
    int*   csr    = (int*)alloc((size_t)ET * 4);
    unsigned int* buf = (unsigned int*)alloc((size_t)ET * 4);
    int*   bcnt   = (int*)alloc((size_t)NBUCK * 4);
    int*   cstart = (int*)alloc((size_t)(NBUCK + 1) * 4);
    int*   cursor = (int*)alloc((size_t)NBUCK * 4);

    const int binWGs = (ET + CHUNK - 1) / CHUNK;
    hipMemsetAsync(bcnt, 0, (size_t)NBUCK * 4, stream);
    k_bin_count<<<binWGs, 256, 0, stream>>>(ei, bcnt);
    k_bin_scan<<<1, 512, 0, stream>>>(bcnt, cstart, cursor, rp);
    k_bin_scatter<<<binWGs, 256, 0, stream>>>(ei, cursor, buf);
    k_bucket_build<<<NBUCK, 256, 0, stream>>>(buf, cstart, rp, csr);
    k_gemm0<<<(N_NODES + 63) / 64, 256, 0, stream>>>(x, W0, a_s0, a_d0, h0b, as0, ad0);
    k_agg0<<<N_NODES / 4, 256, 0, stream>>>((const unsigned int*)h0b, as0, ad0, rp, csr, b0, act);
    k_gemm1<<<(N_NODES + 127) / 128, 128, 0, stream>>>(act, W1, a_s1, a_d1, h1, as1, ad1);
    k_agg1<<<N_NODES / 4, 256, 0, stream>>>(h1, as1, ad1, rp, csr, b1, (float*)d_out);
}

// Round 6
// 357.058 us; speedup vs baseline: 2.3573x; 1.3303x over previous
//
#include <hip/hip_runtime.h>
#include <hip/hip_bf16.h>

#define N_NODES 50000
#define N_EDGES 1600000
#define ET (N_EDGES + N_NODES)   // self-loops appended
#define IN_DIM 256
#define HID 128
#define NCLS 40
#define NEG 0.2f
#define NBUCK 391                // ceil(50000 / 128) buckets of 128 dst nodes
#define CHUNK 4096               // edges per binning workgroup

__device__ __forceinline__ unsigned pk2(float a, float b) {
    __hip_bfloat16 ha = __float2bfloat16(a), hb = __float2bfloat16(b);
    unsigned short ua = *(unsigned short*)&ha, ub = *(unsigned short*)&hb;
    return (unsigned)ua | ((unsigned)ub << 16);
}
__device__ __forceinline__ float blo(unsigned u) { return __uint_as_float(u << 16); }
__device__ __forceinline__ float bhi(unsigned u) { return __uint_as_float(u & 0xffff0000u); }

// ---------------- CSR build: two-level binning (no per-edge global atomics) ----
__global__ __launch_bounds__(256) void k_bin_count(const int* __restrict__ ei,
                                                   int* __restrict__ bcnt) {
    __shared__ int hist[NBUCK];
    int t = threadIdx.x;
    for (int i = t; i < NBUCK; i += 256) hist[i] = 0;
    __syncthreads();
    int base = blockIdx.x * CHUNK;
    #pragma unroll
    for (int j = 0; j < 16; ++j) {
        int i = base + j * 256 + t;
        if (i < ET) {
            int d = (i < N_EDGES) ? ei[N_EDGES + i] : (i - N_EDGES);
            atomicAdd(&hist[d >> 7], 1);
        }
    }
    __syncthreads();
    for (int i = t; i < NBUCK; i += 256) if (hist[i]) atomicAdd(&bcnt[i], hist[i]);
}

__global__ __launch_bounds__(512) void k_bin_scan(const int* __restrict__ bcnt,
                                                  int* __restrict__ cstart,
                                                  int* __restrict__ cursor,
                                                  int* __restrict__ rp) {
    __shared__ int s[512];
    int t = threadIdx.x;
    int v = (t < NBUCK) ? bcnt[t] : 0;
    s[t] = v;
    __syncthreads();
    for (int off = 1; off < 512; off <<= 1) {
        int u = (t >= off) ? s[t - off] : 0;
        __syncthreads();
        s[t] += u;
        __syncthreads();
    }
    int ex = s[t] - v;   // exclusive prefix
    if (t < NBUCK) { cstart[t] = ex; cursor[t] = ex; }
    if (t == 0) { cstart[NBUCK] = ET; rp[N_NODES] = ET; }
}

__global__ __launch_bounds__(256) void k_bin_scatter(const int* __restrict__ ei,
                                                     int* __restrict__ cursor,
                                                     unsigned int* __restrict__ buf) {
    __shared__ int sd[CHUNK];     // staged dst (or -1 past end)
    __shared__ int hist[NBUCK];
    __shared__ int wbase[NBUCK];
    int t = threadIdx.x;
    for (int i = t; i < NBUCK; i += 256) hist[i] = 0;
    __syncthreads();
    int base = blockIdx.x * CHUNK;
    #pragma unroll
    for (int j = 0; j < 16; ++j) {
        int i = base + j * 256 + t;
        int d = -1;
        if (i < ET) d = (i < N_EDGES) ? ei[N_EDGES + i] : (i - N_EDGES);
        sd[j * 256 + t] = d;
        if (d >= 0) atomicAdd(&hist[d >> 7], 1);
    }
    __syncthreads();
    for (int i = t; i < NBUCK; i += 256) {
        int h = hist[i];
        wbase[i] = h ? atomicAdd(&cursor[i], h) : 0;
        hist[i] = 0;              // reuse as running offset
    }
    __syncthreads();
    #pragma unroll
    for (int j = 0; j < 16; ++j) {
        int i = base + j * 256 + t;
        int d = sd[j * 256 + t];
        if (d >= 0) {
            int s_ = (i < N_EDGES) ? ei[i] : d;
            int b = d >> 7;
            int off = atomicAdd(&hist[b], 1);
            buf[wbase[b] + off] = ((unsigned)(d & 127) << 16) | (unsigned)s_;
        }
    }
}

__global__ __launch_bounds__(256) void k_bucket_build(const unsigned int* __restrict__ buf,
                                                      const int* __restrict__ cstart,
                                                      int* __restrict__ rp,
                                                      int* __restrict__ csr) {
    __shared__ int cnt[128], rpl[128], cur[128];
    int b = blockIdx.x;
    int t = threadIdx.x;
    int lo = cstart[b], hi = cstart[b + 1];
    if (t < 128) cnt[t] = 0;
    __syncthreads();
    for (int i = lo + t; i < hi; i += 256) atomicAdd(&cnt[buf[i] >> 16], 1);
    __syncthreads();
    if (t == 0) {
        int run = 0;
        #pragma unroll
        for (int l = 0; l < 128; ++l) { rpl[l] = run; run += cnt[l]; }
    }
    __syncthreads();
    if (t < 128) {
        int node = b * 128 + t;
        if (node < N_NODES) rp[node] = lo + rpl[t];
        cur[t] = 0;
    }
    __syncthreads();
    for (int i = lo + t; i < hi; i += 256) {
        unsigned v = buf[i];
        int dl = v >> 16;
        int off = atomicAdd(&cur[dl], 1);
        csr[lo + rpl[dl] + off] = (int)(v & 0xffffu);
    }
}

// ---------------- Layer 0 GEMM: h0(bf16) = x @ W0^T, fused alpha dots ----------
__global__ __launch_bounds__(256) void k_gemm0(
    const float* __restrict__ x, const float* __restrict__ W0,
    const float* __restrict__ a_s, const float* __restrict__ a_d,
    unsigned short* __restrict__ h0b, float* __restrict__ as0, float* __restrict__ ad0) {
    __shared__ __align__(16) float sx[64 * 68];    // sx[k][n]
    __shared__ __align__(16) float sw[64 * 132];   // sw[k][c]
    int t = threadIdx.x;
    int n0 = blockIdx.x * 64;
    int tn = t & 15, tc = t >> 4;
    float acc[4][8];
    #pragma unroll
    for (int ni = 0; ni < 4; ++ni)
        #pragma unroll
        for (int ci = 0; ci < 8; ++ci) acc[ni][ci] = 0.f;

    for (int k0 = 0; k0 < IN_DIM; k0 += 64) {
        #pragma unroll
        for (int i = 0; i < 4; ++i) {
            int j = i * 256 + t;
            int n = j >> 4, kq = j & 15;
            float4 v = make_float4(0.f, 0.f, 0.f, 0.f);
            if (n0 + n < N_NODES)
                v = *(const float4*)&x[(size_t)(n0 + n) * IN_DIM + k0 + kq * 4];
            int kk = kq * 4;
            sx[(kk + 0) * 68 + n] = v.x;
            sx[(kk + 1) * 68 + n] = v.y;
            sx[(kk + 2) * 68 + n] = v.z;
            sx[(kk + 3) * 68 + n] = v.w;
        }
        #pragma unroll
        for (int i = 0; i < 8; ++i) {
            int j = i * 256 + t;
            int c = j >> 4, kq = j & 15;
            float4 v = *(const float4*)&W0[(size_t)c * IN_DIM + k0 + kq * 4];
            int kk = kq * 4;
            sw[(kk + 0) * 132 + c] = v.x;
            sw[(kk + 1) * 132 + c] = v.y;
            sw[(kk + 2) * 132 + c] = v.z;
            sw[(kk + 3) * 132 + c] = v.w;
        }
        __syncthreads();
        #pragma unroll 8
        for (int k = 0; k < 64; ++k) {
            float4 av  = *(const float4*)&sx[k * 68 + tn * 4];
            float4 bv0 = *(const float4*)&sw[k * 132 + tc * 8];
            float4 bv1 = *(const float4*)&sw[k * 132 + tc * 8 + 4];
            float a_[4] = {av.x, av.y, av.z, av.w};
            float b_[8] = {bv0.x, bv0.y, bv0.z, bv0.w, bv1.x, bv1.y, bv1.z, bv1.w};
            #pragma unroll
            for (int ni = 0; ni < 4; ++ni)
                #pragma unroll
                for (int ci = 0; ci < 8; ++ci)
                    acc[ni][ci] += a_[ni] * b_[ci];
        }
        __syncthreads();
    }

    #pragma unroll
    for (int ni = 0; ni < 4; ++ni) {
        int n = n0 + tn * 4 + ni;
        if (n < N_NODES) {
            uint4 pk;
            pk.x = pk2(acc[ni][0], acc[ni][1]);
            pk.y = pk2(acc[ni][2], acc[ni][3]);
            pk.z = pk2(acc[ni][4], acc[ni][5]);
            pk.w = pk2(acc[ni][6], acc[ni][7]);
            *(uint4*)&h0b[(size_t)n * HID + tc * 8] = pk;
        }
    }
    float avs[8], avd[8];
    #pragma unroll
    for (int ci = 0; ci < 8; ++ci) { avs[ci] = a_s[tc * 8 + ci]; avd[ci] = a_d[tc * 8 + ci]; }
    float* red = sx;  // reuse (post-barrier)
    #pragma unroll
    for (int ni = 0; ni < 4; ++ni) {
        float ps = 0.f, pd = 0.f;
        #pragma unroll
        for (int ci = 0; ci < 8; ++ci) { ps += acc[ni][ci] * avs[ci]; pd += acc[ni][ci] * avd[ci]; }
        red[(tn * 4 + ni) * 16 + tc]        = ps;
        red[1024 + (tn * 4 + ni) * 16 + tc] = pd;
    }
    __syncthreads();
    if (t < 64 && n0 + t < N_NODES) {
        float s = 0.f, d = 0.f;
        #pragma unroll
        for (int q = 0; q < 16; ++q) { s += red[t * 16 + q]; d += red[1024 + t * 16 + q]; }
        as0[n0 + t] = s; ad0[n0 + t] = d;
    }
}

// ---------------- Aggregation layer 0 (bf16 h0): wave/node, half-wave rows -----
// Lanes 0-31 fetch edge j's row, 32-63 edge j+1; 4 pairs unrolled -> 8 rows in flight.
__global__ __launch_bounds__(256) void k_agg0(
    const uint2* __restrict__ h0u, const float* __restrict__ as, const float* __restrict__ ad,
    const int* __restrict__ rp, const int* __restrict__ csr,
    const float* __restrict__ bias, float* __restrict__ act) {
    __shared__ float sw_[4][64];
    __shared__ int   ss_[4][64];
    int wid = threadIdx.x >> 6, lane = threadIdx.x & 63;
    int half = lane >> 5, sl = lane & 31;
    int node = blockIdx.x * 4 + wid;
    int start = rp[node], end = rp[node + 1];
    float ad_n = ad[node];
    float a0 = 0.f, a1 = 0.f, a2 = 0.f, a3 = 0.f, den = 0.f;
    for (int base = start; base < end; base += 64) {
        int mm = end - base; if (mm > 64) mm = 64;
        int s_l = 0; float w_l = 0.f;
        if (lane < mm) {
            s_l = csr[base + lane];
            float e = as[s_l] + ad_n;
            e = (e > 0.f) ? e : NEG * e;
            w_l = __expf(e);
            den += w_l;
        }
        ss_[wid][lane] = s_l;      // slots >= mm hold s=0, w=0 -> contribute 0
        sw_[wid][lane] = w_l;      // wave-local LDS: no barrier needed
        for (int jj = 0; jj < mm; jj += 8) {
            int i0 = jj + half, i1 = i0 + 2, i2 = i0 + 4, i3 = i0 + 6;
            int   s0 = ss_[wid][i0], s1 = ss_[wid][i1], s2 = ss_[wid][i2], s3 = ss_[wid][i3];
            float w0 = sw_[wid][i0], w1 = sw_[wid][i1], w2 = sw_[wid][i2], w3 = sw_[wid][i3];
            uint2 u0 = h0u[(size_t)s0 * 32 + sl];
            uint2 u1 = h0u[(size_t)s1 * 32 + sl];
            uint2 u2 = h0u[(size_t)s2 * 32 + sl];
            uint2 u3 = h0u[(size_t)s3 * 32 + sl];
            a0 += w0 * blo(u0.x) + w1 * blo(u1.x) + w2 * blo(u2.x) + w3 * blo(u3.x);
            a1 += w0 * bhi(u0.x) + w1 * bhi(u1.x) + w2 * bhi(u2.x) + w3 * bhi(u3.x);
            a2 += w0 * blo(u0.y) + w1 * blo(u1.y) + w2 * blo(u2.y) + w3 * blo(u3.y);
            a3 += w0 * bhi(u0.y) + w1 * bhi(u1.y) + w2 * bhi(u2.y) + w3 * bhi(u3.y);
        }
    }
    #pragma unroll
    for (int off = 32; off; off >>= 1) den += __shfl_xor(den, off);
    a0 += __shfl_xor(a0, 32);
    a1 += __shfl_xor(a1, 32);
    a2 += __shfl_xor(a2, 32);
    a3 += __shfl_xor(a3, 32);
    if (half == 0) {
        float inv = 1.f / fmaxf(den, 1e-16f);
        float4 b4 = *(const float4*)&bias[sl * 4];
        float4 r;
        r.x = fmaxf(a0 * inv + b4.x, 0.f);
        r.y = fmaxf(a1 * inv + b4.y, 0.f);
        r.z = fmaxf(a2 * inv + b4.z, 0.f);
        r.w = fmaxf(a3 * inv + b4.w, 0.f);
        *(float4*)&act[(size_t)node * HID + sl * 4] = r;
    }
}

// ---------------- Layer 1 GEMM: h1(bf16) = act @ W1^T, fused alpha dots --------
__global__ __launch_bounds__(128) void k_gemm1(
    const float* __restrict__ act, const float* __restrict__ W1,
    const float* __restrict__ a_s, const float* __restrict__ a_d,
    unsigned short* __restrict__ h1b, float* __restrict__ as1, float* __restrict__ ad1) {
    __shared__ float w1l[NCLS * HID];
    __shared__ float av[NCLS], adv[NCLS];
    int t = threadIdx.x;
    #pragma unroll
    for (int i = 0; i < 10; ++i) {
        int j = t + 128 * i;
        ((float4*)w1l)[j] = ((const float4*)W1)[j];
    }
    if (t < NCLS) { av[t] = a_s[t]; adv[t] = a_d[t]; }
    __syncthreads();
    int n = blockIdx.x * 128 + t;
    if (n >= N_NODES) return;
    const float4* ar = (const float4*)(act + (size_t)n * HID);
    float acc[NCLS];
    #pragma unroll
    for (int c = 0; c < NCLS; ++c) acc[c] = 0.f;
    for (int k0 = 0; k0 < HID; k0 += 4) {
        float4 xv = ar[k0 >> 2];
        #pragma unroll
        for (int c = 0; c < NCLS; ++c) {
            const float4 wv = *(const float4*)&w1l[c * HID + k0];
            acc[c] += xv.x * wv.x + xv.y * wv.y + xv.z * wv.z + xv.w * wv.w;
        }
    }
    float ps = 0.f, pd = 0.f;
    #pragma unroll
    for (int c = 0; c < NCLS; ++c) { ps += acc[c] * av[c]; pd += acc[c] * adv[c]; }
    unsigned pk_[20];
    #pragma unroll
    for (int c = 0; c < 20; ++c) pk_[c] = pk2(acc[2 * c], acc[2 * c + 1]);
    #pragma unroll
    for (int i = 0; i < 5; ++i)
        *(uint4*)&h1b[(size_t)n * NCLS + i * 8] = make_uint4(pk_[4*i], pk_[4*i+1], pk_[4*i+2], pk_[4*i+3]);
    as1[n] = ps; ad1[n] = pd;
}

// ---------------- Aggregation layer 1 (bf16 h1, C=40) → fp32 output ------------
__global__ __launch_bounds__(256) void k_agg1(
    const unsigned int* __restrict__ h1u, const float* __restrict__ as, const float* __restrict__ ad,
    const int* __restrict__ rp, const int* __restrict__ csr,
    const float* __restrict__ bias, float* __restrict__ out) {
    __shared__ float sw_[4][64];
    __shared__ int   ss_[4][64];
    int wid = threadIdx.x >> 6, lane = threadIdx.x & 63;
    int half = lane >> 5, sl = lane & 31;
    int off20 = (sl < 20) ? sl : 0;    // lanes 20-31 read col 0 (discarded)
    int node = blockIdx.x * 4 + wid;
    int start = rp[node], end = rp[node + 1];
    float ad_n = ad[node];
    float a0 = 0.f, a1 = 0.f, den = 0.f;
    for (int base = start; base < end; base += 64) {
        int mm = end - base; if (mm > 64) mm = 64;
        int s_l = 0; float w_l = 0.f;
        if (lane < mm) {
            s_l = csr[base + lane];
            float e = as[s_l] + ad_n;
            e = (e > 0.f) ? e : NEG * e;
            w_l = __expf(e);
            den += w_l;
        }
        ss_[wid][lane] = s_l;
        sw_[wid][lane] = w_l;
        for (int jj = 0; jj < mm; jj += 8) {
            int i0 = jj + half, i1 = i0 + 2, i2 = i0 + 4, i3 = i0 + 6;
            int   s0 = ss_[wid][i0], s1 = ss_[wid][i1], s2 = ss_[wid][i2], s3 = ss_[wid][i3];
            float w0 = sw_[wid][i0], w1 = sw_[wid][i1], w2 = sw_[wid][i2], w3 = sw_[wid][i3];
            unsigned u0 = h1u[(size_t)s0 * 20 + off20];
            unsigned u1 = h1u[(size_t)s1 * 20 + off20];
            unsigned u2 = h1u[(size_t)s2 * 20 + off20];
            unsigned u3 = h1u[(size_t)s3 * 20 + off20];
            a0 += w0 * blo(u0) + w1 * blo(u1) + w2 * blo(u2) + w3 * blo(u3);
            a1 += w0 * bhi(u0) + w1 * bhi(u1) + w2 * bhi(u2) + w3 * bhi(u3);
        }
    }
    #pragma unroll
    for (int off = 32; off; off >>= 1) den += __shfl_xor(den, off);
    a0 += __shfl_xor(a0, 32);
    a1 += __shfl_xor(a1, 32);
    if (half == 0 && sl < 20) {
        float inv = 1.f / fmaxf(den, 1e-16f);
        float2 r;
        r.x = a0 * inv + bias[sl * 2];
        r.y = a1 * inv + bias[sl * 2 + 1];
        *(float2*)&out[(size_t)node * NCLS + sl * 2] = r;
    }
}

extern "C" void kernel_launch(void* const* d_in, const int* in_sizes, int n_in,
                              void* d_out, int out_size, void* d_ws, size_t ws_size,
                              hipStream_t stream) {
    const float* x    = (const float*)d_in[0];
    const int*   ei   = (const int*)d_in[1];
    const float* W0   = (const float*)d_in[2];
    const float* a_s0 = (const float*)d_in[3];
    const float* a_d0 = (const float*)d_in[4];
    const float* b0   = (const float*)d_in[5];
    const float* W1   = (const float*)d_in[6];
    const float* a_s1 = (const float*)d_in[7];
    const float* a_d1 = (const float*)d_in[8];
    const float* b1   = (const float*)d_in[9];

    char* p = (char*)d_ws;
    auto alloc = [&](size_t bytes) { void* q = p; p += (bytes + 255) & ~size_t(255); return q; };
    unsigned short* h0b = (unsigned short*)alloc((size_t)N_NODES * HID * 2);        // bf16
    unsigned short* h1b = (unsigned short*)alloc(((size_t)N_NODES * NCLS + 32) * 2); // bf16 (+pad)
    float* act    = (float*)alloc((size_t)N_NODES * HID * 4);
    float* as0    = (float*)alloc((size_t)N_NODES * 4);
    float* ad0    = (float*)alloc((size_t)N_NODES * 4);
    float* as1    = (float*)alloc((size_t)N_NODES * 4);
    float* ad1    = (float*)alloc((size_t)N_NODES * 4);
    int*   rp     = (int*)alloc((size_t)(N_NODES + 1) * 4);
    int*   csr    = (int*)alloc((size_t)ET * 4);
    unsigned int* buf = (unsigned int*)alloc((size_t)ET * 4);
    int*   bcnt   = (int*)alloc((size_t)NBUCK * 4);
    int*   cstart = (int*)alloc((size_t)(NBUCK + 1) * 4);
    int*   cursor = (int*)alloc((size_t)NBUCK * 4);

    const int binWGs = (ET + CHUNK - 1) / CHUNK;
    hipMemsetAsync(bcnt, 0, (size_t)NBUCK * 4, stream);
    k_bin_count<<<binWGs, 256, 0, stream>>>(ei, bcnt);
    k_bin_scan<<<1, 512, 0, stream>>>(bcnt, cstart, cursor, rp);
    k_bin_scatter<<<binWGs, 256, 0, stream>>>(ei, cursor, buf);
    k_bucket_build<<<NBUCK, 256, 0, stream>>>(buf, cstart, rp, csr);
    k_gemm0<<<(N_NODES + 63) / 64, 256, 0, stream>>>(x, W0, a_s0, a_d0, h0b, as0, ad0);
    k_agg0<<<N_NODES / 4, 256, 0, stream>>>((const uint2*)h0b, as0, ad0, rp, csr, b0, act);
    k_gemm1<<<(N_NODES + 127) / 128, 128, 0, stream>>>(act, W1, a_s1, a_d1, h1b, as1, ad1);
    k_agg1<<<N_NODES / 4, 256, 0, stream>>>((const unsigned int*)h1b, as1, ad1, rp, csr, b1, (float*)d_out);
}

// Round 7
// 302.564 us; speedup vs baseline: 2.7819x; 1.1801x over previous
//
#include <hip/hip_runtime.h>
#include <hip/hip_bf16.h>

#define N_NODES 50000
#define N_EDGES 1600000
#define ET (N_EDGES + N_NODES)   // self-loops appended
#define IN_DIM 256
#define HID 128
#define NCLS 40
#define NEG 0.2f
#define NBUCK 391                // ceil(50000 / 128) buckets of 128 dst nodes
#define CHUNK 4096               // edges per binning workgroup

typedef short bf16x8 __attribute__((ext_vector_type(8)));
typedef float f32x4  __attribute__((ext_vector_type(4)));

__device__ __forceinline__ unsigned pk2(float a, float b) {
    __hip_bfloat16 ha = __float2bfloat16(a), hb = __float2bfloat16(b);
    unsigned short ua = *(unsigned short*)&ha, ub = *(unsigned short*)&hb;
    return (unsigned)ua | ((unsigned)ub << 16);
}
__device__ __forceinline__ float blo(unsigned u) { return __uint_as_float(u << 16); }
__device__ __forceinline__ float bhi(unsigned u) { return __uint_as_float(u & 0xffff0000u); }

// ---------------- CSR build: two-level binning (no per-edge global atomics) ----
__global__ __launch_bounds__(256) void k_bin_count(const int* __restrict__ ei,
                                                   int* __restrict__ bcnt) {
    __shared__ int hist[NBUCK];
    int t = threadIdx.x;
    for (int i = t; i < NBUCK; i += 256) hist[i] = 0;
    __syncthreads();
    int base = blockIdx.x * CHUNK;
    #pragma unroll
    for (int j = 0; j < 16; ++j) {
        int i = base + j * 256 + t;
        if (i < ET) {
            int d = (i < N_EDGES) ? ei[N_EDGES + i] : (i - N_EDGES);
            atomicAdd(&hist[d >> 7], 1);
        }
    }
    __syncthreads();
    for (int i = t; i < NBUCK; i += 256) if (hist[i]) atomicAdd(&bcnt[i], hist[i]);
}

__global__ __launch_bounds__(512) void k_bin_scan(const int* __restrict__ bcnt,
                                                  int* __restrict__ cstart,
                                                  int* __restrict__ cursor,
                                                  int* __restrict__ rp) {
    __shared__ int s[512];
    int t = threadIdx.x;
    int v = (t < NBUCK) ? bcnt[t] : 0;
    s[t] = v;
    __syncthreads();
    for (int off = 1; off < 512; off <<= 1) {
        int u = (t >= off) ? s[t - off] : 0;
        __syncthreads();
        s[t] += u;
        __syncthreads();
    }
    int ex = s[t] - v;   // exclusive prefix
    if (t < NBUCK) { cstart[t] = ex; cursor[t] = ex; }
    if (t == 0) { cstart[NBUCK] = ET; rp[N_NODES] = ET; }
}

__global__ __launch_bounds__(256) void k_bin_scatter(const int* __restrict__ ei,
                                                     int* __restrict__ cursor,
                                                     unsigned int* __restrict__ buf) {
    __shared__ int sd[CHUNK];     // staged dst (or -1 past end)
    __shared__ int hist[NBUCK];
    __shared__ int wbase[NBUCK];
    int t = threadIdx.x;
    for (int i = t; i < NBUCK; i += 256) hist[i] = 0;
    __syncthreads();
    int base = blockIdx.x * CHUNK;
    #pragma unroll
    for (int j = 0; j < 16; ++j) {
        int i = base + j * 256 + t;
        int d = -1;
        if (i < ET) d = (i < N_EDGES) ? ei[N_EDGES + i] : (i - N_EDGES);
        sd[j * 256 + t] = d;
        if (d >= 0) atomicAdd(&hist[d >> 7], 1);
    }
    __syncthreads();
    for (int i = t; i < NBUCK; i += 256) {
        int h = hist[i];
        wbase[i] = h ? atomicAdd(&cursor[i], h) : 0;
        hist[i] = 0;              // reuse as running offset
    }
    __syncthreads();
    #pragma unroll
    for (int j = 0; j < 16; ++j) {
        int i = base + j * 256 + t;
        int d = sd[j * 256 + t];
        if (d >= 0) {
            int s_ = (i < N_EDGES) ? ei[i] : d;
            int b = d >> 7;
            int off = atomicAdd(&hist[b], 1);
            buf[wbase[b] + off] = ((unsigned)(d & 127) << 16) | (unsigned)s_;
        }
    }
}

__global__ __launch_bounds__(256) void k_bucket_build(const unsigned int* __restrict__ buf,
                                                      const int* __restrict__ cstart,
                                                      int* __restrict__ rp,
                                                      int* __restrict__ csr) {
    __shared__ int cnt[128], rpl[128], cur[128];
    int b = blockIdx.x;
    int t = threadIdx.x;
    int lo = cstart[b], hi = cstart[b + 1];
    if (t < 128) cnt[t] = 0;
    __syncthreads();
    for (int i = lo + t; i < hi; i += 256) atomicAdd(&cnt[buf[i] >> 16], 1);
    __syncthreads();
    if (t == 0) {
        int run = 0;
        #pragma unroll
        for (int l = 0; l < 128; ++l) { rpl[l] = run; run += cnt[l]; }
    }
    __syncthreads();
    if (t < 128) {
        int node = b * 128 + t;
        if (node < N_NODES) rp[node] = lo + rpl[t];
        cur[t] = 0;
    }
    __syncthreads();
    for (int i = lo + t; i < hi; i += 256) {
        unsigned v = buf[i];
        int dl = v >> 16;
        int off = atomicAdd(&cur[dl], 1);
        csr[lo + rpl[dl] + off] = (int)(v & 0xffffu);
    }
}

// ---------------- Layer 0 GEMM (MFMA bf16): h0(bf16) = x @ W0^T + alpha dots ---
// 256 thr / 4 waves; tile 64 nodes x 128 cols; BK=64 staged bf16 in LDS.
// LDS row stride 72 bf16 (36 dwords): staging writes & frag reads <=2-way (free).
// Frag layouts (guide-verified): A/B^T [m=lane&15][k=(lane>>4)*8+j];
// C/D col=lane&15, row=(lane>>4)*4+reg.
__global__ __launch_bounds__(256) void k_gemm0(
    const float* __restrict__ x, const float* __restrict__ W0,
    const float* __restrict__ a_s, const float* __restrict__ a_d,
    unsigned short* __restrict__ h0b, float* __restrict__ as0, float* __restrict__ ad0) {
    __shared__ unsigned sA[64 * 36];    // bf16 [64 rows][72]
    __shared__ unsigned sB[128 * 36];   // bf16 [128 cols][72]
    int t = threadIdx.x;
    int n0 = blockIdx.x * 64;
    int w = t >> 6, lane = t & 63;
    int rw = lane & 15, q = lane >> 4;
    f32x4 acc[8];
    #pragma unroll
    for (int n = 0; n < 8; ++n) acc[n] = (f32x4){0.f, 0.f, 0.f, 0.f};

    for (int kc = 0; kc < IN_DIM; kc += 64) {
        // stage A: 64 rows x 64 k (flat 1024 float4, coalesced 256B runs)
        #pragma unroll
        for (int i = 0; i < 4; ++i) {
            int f = i * 256 + t;
            int r = f >> 4, fq = f & 15;
            float4 v = make_float4(0.f, 0.f, 0.f, 0.f);
            if (n0 + r < N_NODES)
                v = *(const float4*)&x[(size_t)(n0 + r) * IN_DIM + kc + fq * 4];
            *(uint2*)&sA[r * 36 + fq * 2] = make_uint2(pk2(v.x, v.y), pk2(v.z, v.w));
        }
        // stage B: 128 cols x 64 k (flat 2048 float4)
        #pragma unroll
        for (int i = 0; i < 8; ++i) {
            int f = i * 256 + t;
            int c = f >> 4, fq = f & 15;
            float4 v = *(const float4*)&W0[(size_t)c * IN_DIM + kc + fq * 4];
            *(uint2*)&sB[c * 36 + fq * 2] = make_uint2(pk2(v.x, v.y), pk2(v.z, v.w));
        }
        __syncthreads();
        #pragma unroll
        for (int ks = 0; ks < 2; ++ks) {
            bf16x8 af = *(const bf16x8*)((const unsigned short*)sA + (16 * w + rw) * 72 + ks * 32 + q * 8);
            #pragma unroll
            for (int n = 0; n < 8; ++n) {
                bf16x8 bfr = *(const bf16x8*)((const unsigned short*)sB + (n * 16 + rw) * 72 + ks * 32 + q * 8);
                acc[n] = __builtin_amdgcn_mfma_f32_16x16x32_bf16(af, bfr, acc[n], 0, 0, 0);
            }
        }
        __syncthreads();
    }

    // epilogue: bf16 h0 stores + fused alpha dots
    float asv[8], adv[8];
    #pragma unroll
    for (int n = 0; n < 8; ++n) { asv[n] = a_s[n * 16 + rw]; adv[n] = a_d[n * 16 + rw]; }
    float ps[4] = {0.f, 0.f, 0.f, 0.f}, pd[4] = {0.f, 0.f, 0.f, 0.f};
    #pragma unroll
    for (int n = 0; n < 8; ++n)
        #pragma unroll
        for (int reg = 0; reg < 4; ++reg) {
            float vv = acc[n][reg];
            ps[reg] += vv * asv[n];
            pd[reg] += vv * adv[n];
        }
    #pragma unroll
    for (int reg = 0; reg < 4; ++reg) {
        int node = n0 + 16 * w + q * 4 + reg;
        if (node < N_NODES) {
            #pragma unroll
            for (int n = 0; n < 8; ++n) {
                __hip_bfloat16 hb = __float2bfloat16(acc[n][reg]);
                h0b[(size_t)node * HID + n * 16 + rw] = *(unsigned short*)&hb;
            }
        }
    }
    #pragma unroll
    for (int reg = 0; reg < 4; ++reg)
        #pragma unroll
        for (int off = 1; off < 16; off <<= 1) {
            ps[reg] += __shfl_xor(ps[reg], off);
            pd[reg] += __shfl_xor(pd[reg], off);
        }
    if (rw == 0) {
        #pragma unroll
        for (int reg = 0; reg < 4; ++reg) {
            int node = n0 + 16 * w + q * 4 + reg;
            if (node < N_NODES) { as0[node] = ps[reg]; ad0[node] = pd[reg]; }
        }
    }
}

// ---------------- Aggregation layer 0 (bf16 h0): wave/node, half-wave rows -----
__global__ __launch_bounds__(256) void k_agg0(
    const uint2* __restrict__ h0u, const float* __restrict__ as, const float* __restrict__ ad,
    const int* __restrict__ rp, const int* __restrict__ csr,
    const float* __restrict__ bias, float* __restrict__ act) {
    __shared__ float sw_[4][64];
    __shared__ int   ss_[4][64];
    int wid = threadIdx.x >> 6, lane = threadIdx.x & 63;
    int half = lane >> 5, sl = lane & 31;
    int node = blockIdx.x * 4 + wid;
    int start = rp[node], end = rp[node + 1];
    float ad_n = ad[node];
    float a0 = 0.f, a1 = 0.f, a2 = 0.f, a3 = 0.f, den = 0.f;
    for (int base = start; base < end; base += 64) {
        int mm = end - base; if (mm > 64) mm = 64;
        int s_l = 0; float w_l = 0.f;
        if (lane < mm) {
            s_l = csr[base + lane];
            float e = as[s_l] + ad_n;
            e = (e > 0.f) ? e : NEG * e;
            w_l = __expf(e);
            den += w_l;
        }
        ss_[wid][lane] = s_l;      // slots >= mm hold s=0, w=0 -> contribute 0
        sw_[wid][lane] = w_l;      // wave-local LDS: no barrier needed
        for (int jj = 0; jj < mm; jj += 8) {
            int i0 = jj + half, i1 = i0 + 2, i2 = i0 + 4, i3 = i0 + 6;
            int   s0 = ss_[wid][i0], s1 = ss_[wid][i1], s2 = ss_[wid][i2], s3 = ss_[wid][i3];
            float w0 = sw_[wid][i0], w1 = sw_[wid][i1], w2 = sw_[wid][i2], w3 = sw_[wid][i3];
            uint2 u0 = h0u[(size_t)s0 * 32 + sl];
            uint2 u1 = h0u[(size_t)s1 * 32 + sl];
            uint2 u2 = h0u[(size_t)s2 * 32 + sl];
            uint2 u3 = h0u[(size_t)s3 * 32 + sl];
            a0 += w0 * blo(u0.x) + w1 * blo(u1.x) + w2 * blo(u2.x) + w3 * blo(u3.x);
            a1 += w0 * bhi(u0.x) + w1 * bhi(u1.x) + w2 * bhi(u2.x) + w3 * bhi(u3.x);
            a2 += w0 * blo(u0.y) + w1 * blo(u1.y) + w2 * blo(u2.y) + w3 * blo(u3.y);
            a3 += w0 * bhi(u0.y) + w1 * bhi(u1.y) + w2 * bhi(u2.y) + w3 * bhi(u3.y);
        }
    }
    #pragma unroll
    for (int off = 32; off; off >>= 1) den += __shfl_xor(den, off);
    a0 += __shfl_xor(a0, 32);
    a1 += __shfl_xor(a1, 32);
    a2 += __shfl_xor(a2, 32);
    a3 += __shfl_xor(a3, 32);
    if (half == 0) {
        float inv = 1.f / fmaxf(den, 1e-16f);
        float4 b4 = *(const float4*)&bias[sl * 4];
        float4 r;
        r.x = fmaxf(a0 * inv + b4.x, 0.f);
        r.y = fmaxf(a1 * inv + b4.y, 0.f);
        r.z = fmaxf(a2 * inv + b4.z, 0.f);
        r.w = fmaxf(a3 * inv + b4.w, 0.f);
        *(float4*)&act[(size_t)node * HID + sl * 4] = r;
    }
}

// ---------------- Layer 1 GEMM: h1(bf16) = act @ W1^T, fused alpha dots --------
__global__ __launch_bounds__(128) void k_gemm1(
    const float* __restrict__ act, const float* __restrict__ W1,
    const float* __restrict__ a_s, const float* __restrict__ a_d,
    unsigned short* __restrict__ h1b, float* __restrict__ as1, float* __restrict__ ad1) {
    __shared__ float w1l[NCLS * HID];
    __shared__ float av[NCLS], adv[NCLS];
    int t = threadIdx.x;
    #pragma unroll
    for (int i = 0; i < 10; ++i) {
        int j = t + 128 * i;
        ((float4*)w1l)[j] = ((const float4*)W1)[j];
    }
    if (t < NCLS) { av[t] = a_s[t]; adv[t] = a_d[t]; }
    __syncthreads();
    int n = blockIdx.x * 128 + t;
    if (n >= N_NODES) return;
    const float4* ar = (const float4*)(act + (size_t)n * HID);
    float acc[NCLS];
    #pragma unroll
    for (int c = 0; c < NCLS; ++c) acc[c] = 0.f;
    for (int k0 = 0; k0 < HID; k0 += 4) {
        float4 xv = ar[k0 >> 2];
        #pragma unroll
        for (int c = 0; c < NCLS; ++c) {
            const float4 wv = *(const float4*)&w1l[c * HID + k0];
            acc[c] += xv.x * wv.x + xv.y * wv.y + xv.z * wv.z + xv.w * wv.w;
        }
    }
    float ps = 0.f, pd = 0.f;
    #pragma unroll
    for (int c = 0; c < NCLS; ++c) { ps += acc[c] * av[c]; pd += acc[c] * adv[c]; }
    unsigned pk_[20];
    #pragma unroll
    for (int c = 0; c < 20; ++c) pk_[c] = pk2(acc[2 * c], acc[2 * c + 1]);
    #pragma unroll
    for (int i = 0; i < 5; ++i)
        *(uint4*)&h1b[(size_t)n * NCLS + i * 8] = make_uint4(pk_[4*i], pk_[4*i+1], pk_[4*i+2], pk_[4*i+3]);
    as1[n] = ps; ad1[n] = pd;
}

// ---------------- Aggregation layer 1 (bf16 h1, C=40) → fp32 output ------------
__global__ __launch_bounds__(256) void k_agg1(
    const unsigned int* __restrict__ h1u, const float* __restrict__ as, const float* __restrict__ ad,
    const int* __restrict__ rp, const int* __restrict__ csr,
    const float* __restrict__ bias, float* __restrict__ out) {
    __shared__ float sw_[4][64];
    __shared__ int   ss_[4][64];
    int wid = threadIdx.x >> 6, lane = threadIdx.x & 63;
    int half = lane >> 5, sl = lane & 31;
    int off20 = (sl < 20) ? sl : 0;    // lanes 20-31 read col 0 (discarded)
    int node = blockIdx.x * 4 + wid;
    int start = rp[node], end = rp[node + 1];
    float ad_n = ad[node];
    float a0 = 0.f, a1 = 0.f, den = 0.f;
    for (int base = start; base < end; base += 64) {
        int mm = end - base; if (mm > 64) mm = 64;
        int s_l = 0; float w_l = 0.f;
        if (lane < mm) {
            s_l = csr[base + lane];
            float e = as[s_l] + ad_n;
            e = (e > 0.f) ? e : NEG * e;
            w_l = __expf(e);
            den += w_l;
        }
        ss_[wid][lane] = s_l;
        sw_[wid][lane] = w_l;
        for (int jj = 0; jj < mm; jj += 8) {
            int i0 = jj + half, i1 = i0 + 2, i2 = i0 + 4, i3 = i0 + 6;
            int   s0 = ss_[wid][i0], s1 = ss_[wid][i1], s2 = ss_[wid][i2], s3 = ss_[wid][i3];
            float w0 = sw_[wid][i0], w1 = sw_[wid][i1], w2 = sw_[wid][i2], w3 = sw_[wid][i3];
            unsigned u0 = h1u[(size_t)s0 * 20 + off20];
            unsigned u1 = h1u[(size_t)s1 * 20 + off20];
            unsigned u2 = h1u[(size_t)s2 * 20 + off20];
            unsigned u3 = h1u[(size_t)s3 * 20 + off20];
            a0 += w0 * blo(u0) + w1 * blo(u1) + w2 * blo(u2) + w3 * blo(u3);
            a1 += w0 * bhi(u0) + w1 * bhi(u1) + w2 * bhi(u2) + w3 * bhi(u3);
        }
    }
    #pragma unroll
    for (int off = 32; off; off >>= 1) den += __shfl_xor(den, off);
    a0 += __shfl_xor(a0, 32);
    a1 += __shfl_xor(a1, 32);
    if (half == 0 && sl < 20) {
        float inv = 1.f / fmaxf(den, 1e-16f);
        float2 r;
        r.x = a0 * inv + bias[sl * 2];
        r.y = a1 * inv + bias[sl * 2 + 1];
        *(float2*)&out[(size_t)node * NCLS + sl * 2] = r;
    }
}

extern "C" void kernel_launch(void* const* d_in, const int* in_sizes, int n_in,
                              void* d_out, int out_size, void* d_ws, size_t ws_size,
                              hipStream_t stream) {
    const float* x    = (const float*)d_in[0];
    const int*   ei   = (const int*)d_in[1];
    const float* W0   = (const float*)d_in[2];
    const float* a_s0 = (const float*)d_in[3];
    const float* a_d0 = (const float*)d_in[4];
    const float* b0   = (const float*)d_in[5];
    const float* W1   = (const float*)d_in[6];
    const float* a_s1 = (const float*)d_in[7];
    const float* a_d1 = (const float*)d_in[8];
    const float* b1   = (const float*)d_in[9];

    char* p = (char*)d_ws;
    auto alloc = [&](size_t bytes) { void* q = p; p += (bytes + 255) & ~size_t(255); return q; };
    unsigned short* h0b = (unsigned short*)alloc((size_t)N_NODES * HID * 2);        // bf16
    unsigned short* h1b = (unsigned short*)alloc(((size_t)N_NODES * NCLS + 32) * 2); // bf16 (+pad)
    float* act    = (float*)alloc((size_t)N_NODES * HID * 4);
    float* as0    = (float*)alloc((size_t)N_NODES * 4);
    float* ad0    = (float*)alloc((size_t)N_NODES * 4);
    float* as1    = (float*)alloc((size_t)N_NODES * 4);
    float* ad1    = (float*)alloc((size_t)N_NODES * 4);
    int*   rp     = (int*)alloc((size_t)(N_NODES + 1) * 4);
    int*   csr    = (int*)alloc((size_t)ET * 4);
    unsigned int* buf = (unsigned int*)alloc((size_t)ET * 4);
    int*   bcnt   = (int*)alloc((size_t)NBUCK * 4);
    int*   cstart = (int*)alloc((size_t)(NBUCK + 1) * 4);
    int*   cursor = (int*)alloc((size_t)NBUCK * 4);

    const int binWGs = (ET + CHUNK - 1) / CHUNK;
    hipMemsetAsync(bcnt, 0, (size_t)NBUCK * 4, stream);
    k_bin_count<<<binWGs, 256, 0, stream>>>(ei, bcnt);
    k_bin_scan<<<1, 512, 0, stream>>>(bcnt, cstart, cursor, rp);
    k_bin_scatter<<<binWGs, 256, 0, stream>>>(ei, cursor, buf);
    k_bucket_build<<<NBUCK, 256, 0, stream>>>(buf, cstart, rp, csr);
    k_gemm0<<<(N_NODES + 63) / 64, 256, 0, stream>>>(x, W0, a_s0, a_d0, h0b, as0, ad0);
    k_agg0<<<N_NODES / 4, 256, 0, stream>>>((const uint2*)h0b, as0, ad0, rp, csr, b0, act);
    k_gemm1<<<(N_NODES + 127) / 128, 128, 0, stream>>>(act, W1, a_s1, a_d1, h1b, as1, ad1);
    k_agg1<<<N_NODES / 4, 256, 0, stream>>>((const unsigned int*)h1b, as1, ad1, rp, csr, b1, (float*)d_out);
}